// Round 6
// baseline (1242.509 us; speedup 1.0000x reference)
//
#include <hip/hip_runtime.h>
#include <hip/hip_bf16.h>
#include <math.h>

#define T_STEPS 512
#define BATCH   64
#define DIM     1024
#define NB      16
#define NS      64
#define TOK     (T_STEPS*BATCH)        // 32768
#define SELROWS (2*TOK + NB*64)        // 66560 (spare rows for tile padding)
#define MAXTILES ((2*TOK)/64 + NB)     // 1040

// ---- workspace layout (float offsets) ----
#define WS_LOGITS 0                        // TOK*16
#define WS_W      (WS_LOGITS + TOK*NB)     // TOK*16 softmax weights
#define WS_Q      (WS_W + TOK*NB)          // TOK*64
#define WS_SEL    (WS_Q + TOK*NS)          // TOK ints (m1|m2<<8)
#define WS_TOKL   (WS_SEL + TOK)           // NB*TOK ints
#define WS_SELL   (WS_TOKL + NB*TOK)       // NB*TOK ints
#define WS_CNT    (WS_SELL + NB*TOK)       // 16 ints
#define WS_TILE   (WS_CNT + 16)            // 32 ints
#define WS_KVSEL  (WS_TILE + 32)           // SELROWS*192 floats
#define WS_WHI    (WS_KVSEL + SELROWS*192) // 16*192*1024 bf16 = 1572864 float-slots
#define WS_WLO    (WS_WHI + (NB*192*DIM)/2)

typedef __attribute__((ext_vector_type(8))) short short8x;
typedef __attribute__((ext_vector_type(4))) float f32x4;

__device__ __forceinline__ short f2bf_hi(float f, float& rem) {
  __hip_bfloat16 h = __float2bfloat16(f);
  rem = f - __bfloat162float(h);
  return *(short*)&h;
}
__device__ __forceinline__ short f2bf(float f) {
  __hip_bfloat16 h = __float2bfloat16(f);
  return *(short*)&h;
}
__device__ __forceinline__ float sigm(float x) {
  return __builtin_amdgcn_rcpf(1.f + __builtin_amdgcn_exp2f(-1.4426950408889634f*x));
}
__device__ __forceinline__ float fast_tanh(float v) {
  v = fminf(10.f, fmaxf(-10.f, v));
  float e = __builtin_amdgcn_exp2f(2.8853900817779268f*v);
  return 1.f - 2.f*__builtin_amdgcn_rcpf(e + 1.f);
}

// ---------------- router logits (unchanged) ---------------------------------
__global__ __launch_bounds__(256) void logits_kernel(
    const float* __restrict__ x, const float* __restrict__ Wr,
    float* __restrict__ logits)
{
  const int wv   = __builtin_amdgcn_readfirstlane(threadIdx.x >> 6);
  const int lane = threadIdx.x & 63;
  const int tok  = blockIdx.x*64 + lane;
  const float* xr = x + (size_t)tok*DIM;
  const float* w0 = Wr + (size_t)(4*wv)*DIM;
  double acc[4] = {0.0, 0.0, 0.0, 0.0};
  for (int k0 = 0; k0 < DIM; k0 += 32) {
    float4 xv[8];
    #pragma unroll
    for (int i = 0; i < 8; i++) xv[i] = *(const float4*)&xr[k0 + 4*i];
    #pragma unroll
    for (int cc = 0; cc < 4; cc++) {
      const float* wr = w0 + (size_t)cc*DIM + k0;
      double s = 0.0;
      #pragma unroll
      for (int i = 0; i < 8; i++) {
        float4 w4 = *(const float4*)&wr[4*i];
        s += ((double)xv[i].x*(double)w4.x + (double)xv[i].y*(double)w4.y)
           + ((double)xv[i].z*(double)w4.z + (double)xv[i].w*(double)w4.w);
      }
      acc[cc] += s;
    }
  }
  #pragma unroll
  for (int cc = 0; cc < 4; cc++)
    logits[(size_t)tok*NB + 4*wv + cc] = (float)acc[cc];
}

// ---------------- routing (unchanged) ---------------------------------------
__global__ __launch_bounds__(256) void route_kernel(
    const float* __restrict__ logits, float* __restrict__ w,
    int* __restrict__ selp, int* __restrict__ toklist,
    int* __restrict__ sellist, int* __restrict__ cnt)
{
  const int tok = blockIdx.x*256 + threadIdx.x;
  const float* lg = logits + (size_t)tok*NB;
  float lv[NB];
  #pragma unroll
  for (int l = 0; l < NB; l++) lv[l] = lg[l];
  float v1 = lv[0]; int m1 = 0;
  #pragma unroll
  for (int l = 1; l < NB; l++) if (lv[l] > v1) { v1 = lv[l]; m1 = l; }
  float v2 = -3.4e38f; int m2 = 0;
  #pragma unroll
  for (int l = 0; l < NB; l++) if (l != m1 && lv[l] > v2) { v2 = lv[l]; m2 = l; }
  float ev[NB], sum = 0.f;
  #pragma unroll
  for (int l = 0; l < NB; l++) { ev[l] = __expf(lv[l] - v1); sum += ev[l]; }
  const float rs = __builtin_amdgcn_rcpf(sum);
  #pragma unroll
  for (int l = 0; l < NB; l++) w[(size_t)tok*NB + l] = ev[l] * rs;
  selp[tok] = m1 | (m2 << 8);
  int p1 = atomicAdd(&cnt[m1], 1);
  toklist[m1*TOK + p1] = tok;  sellist[m1*TOK + p1] = 2*tok;
  int p2 = atomicAdd(&cnt[m2], 1);
  toklist[m2*TOK + p2] = tok;  sellist[m2*TOK + p2] = 2*tok + 1;
}

// ---------------- tile prefix + pad tail tiles (unchanged) -------------------
__global__ void prefix_kernel(const int* __restrict__ cnt, int* __restrict__ tile,
                              int* __restrict__ toklist, int* __restrict__ sellist)
{
  __shared__ int off[NB+1];
  if (threadIdx.x == 0) {
    int a = 0;
    for (int c = 0; c < NB; c++) { off[c] = a; tile[c] = a; a += (cnt[c] + 63) >> 6; }
    off[NB] = a; tile[NB] = a;
  }
  __syncthreads();
  for (int c = 0; c < NB; c++) {
    const int s = cnt[c], e = (off[c+1] - off[c]) << 6;
    for (int i = s + threadIdx.x; i < e; i += 256) {
      toklist[c*TOK + i] = 0;
      sellist[c*TOK + i] = 2*TOK + c*64 + (i & 63);
    }
  }
}

// ---------------- W split-cast (unchanged) -----------------------------------
__global__ void wcast_kernel(const float* __restrict__ Wkv,
                             const float* __restrict__ Wb,
                             short* __restrict__ Whi, short* __restrict__ Wlo)
{
  const int R = blockIdx.x, c = R/192, r = R%192;
  const float* src = (r < 128) ? Wkv + ((size_t)c*128 + r)*DIM
                               : Wb  + ((size_t)c*64 + (r-128))*DIM;
  const int k = threadIdx.x*4;
  float4 f = *(const float4*)&src[k];
  float ff[4] = {f.x, f.y, f.z, f.w};
  short* dh = Whi + (size_t)R*DIM + k;
  short* dl = Wlo + (size_t)R*DIM + k;
  #pragma unroll
  for (int e = 0; e < 4; e++) {
    float rem;
    dh[e] = f2bf_hi(ff[e], rem);
    dl[e] = f2bf(rem);
  }
}

// ---------------- gather-GEMM: bf16x3 MFMA (unchanged) ----------------------
__global__ __launch_bounds__(256) void gather_gemm_kernel(
    const float* __restrict__ x,
    const short* __restrict__ Whi, const short* __restrict__ Wlo,
    const float* __restrict__ b_beta,
    const int* __restrict__ tileoff, const int* __restrict__ toklist,
    const int* __restrict__ sellist, float* __restrict__ kvsel)
{
  __shared__ short Ahi[64][40];
  __shared__ short Alo[64][40];
  __shared__ int tl[64], sl[64];
  const int tile = blockIdx.x;
  if (tile >= tileoff[NB]) return;
  int c = 0;
  while (c < NB-1 && tile >= tileoff[c+1]) c++;
  const int ti = tile - tileoff[c];
  const int tid = threadIdx.x;
  if (tid < 64) {
    tl[tid] = toklist[c*TOK + (ti<<6) + tid];
    sl[tid] = sellist[c*TOK + (ti<<6) + tid];
  }
  __syncthreads();

  const int wv = tid >> 6, l = tid & 63;
  const int arow = tid >> 2, akseg = (tid & 3) << 3;
  const float* aptr = x + (size_t)tl[arow]*DIM + akseg;
  const short* bh_p = Whi + ((size_t)c*192 + wv*48 + (l & 15))*DIM + ((l >> 4) << 3);
  const short* bl_p = Wlo + ((size_t)c*192 + wv*48 + (l & 15))*DIM + ((l >> 4) << 3);

  f32x4 acc[4][3];
  #pragma unroll
  for (int mt = 0; mt < 4; mt++)
    #pragma unroll
    for (int nt = 0; nt < 3; nt++) acc[mt][nt] = (f32x4){0.f,0.f,0.f,0.f};

  float4 af[2][2];
  short8x bh[2][3], bl[2][3];
  af[0][0] = *(const float4*)&aptr[0];
  af[0][1] = *(const float4*)&aptr[4];
  #pragma unroll
  for (int nt = 0; nt < 3; nt++) {
    bh[0][nt] = *(const short8x*)&bh_p[nt*16*DIM];
    bl[0][nt] = *(const short8x*)&bl_p[nt*16*DIM];
  }

  #pragma unroll 2
  for (int ch = 0; ch < 32; ch++) {
    const int p = ch & 1, pn = p ^ 1;
    {
      float f8[8] = {af[p][0].x, af[p][0].y, af[p][0].z, af[p][0].w,
                     af[p][1].x, af[p][1].y, af[p][1].z, af[p][1].w};
      short h8[8], l8[8];
      #pragma unroll
      for (int e = 0; e < 8; e++) {
        float rem;
        h8[e] = f2bf_hi(f8[e], rem);
        l8[e] = f2bf(rem);
      }
      *(short8x*)&Ahi[arow][akseg] = *(short8x*)h8;
      *(short8x*)&Alo[arow][akseg] = *(short8x*)l8;
    }
    if (ch < 31) {
      af[pn][0] = *(const float4*)&aptr[(ch+1)*32];
      af[pn][1] = *(const float4*)&aptr[(ch+1)*32 + 4];
    }
    __syncthreads();
    if (ch < 31) {
      #pragma unroll
      for (int nt = 0; nt < 3; nt++) {
        bh[pn][nt] = *(const short8x*)&bh_p[nt*16*DIM + (ch+1)*32];
        bl[pn][nt] = *(const short8x*)&bl_p[nt*16*DIM + (ch+1)*32];
      }
    }
    short8x ah[4], al[4];
    #pragma unroll
    for (int mt = 0; mt < 4; mt++) {
      ah[mt] = *(const short8x*)&Ahi[mt*16 + (l & 15)][(l >> 4) << 3];
      al[mt] = *(const short8x*)&Alo[mt*16 + (l & 15)][(l >> 4) << 3];
    }
    #pragma unroll
    for (int mt = 0; mt < 4; mt++)
      #pragma unroll
      for (int nt = 0; nt < 3; nt++) {
        acc[mt][nt] = __builtin_amdgcn_mfma_f32_16x16x32_bf16(ah[mt], bh[p][nt], acc[mt][nt], 0, 0, 0);
        acc[mt][nt] = __builtin_amdgcn_mfma_f32_16x16x32_bf16(ah[mt], bl[p][nt], acc[mt][nt], 0, 0, 0);
        acc[mt][nt] = __builtin_amdgcn_mfma_f32_16x16x32_bf16(al[mt], bh[p][nt], acc[mt][nt], 0, 0, 0);
      }
    __syncthreads();
  }

  #pragma unroll
  for (int mt = 0; mt < 4; mt++) {
    #pragma unroll
    for (int reg = 0; reg < 4; reg++) {
      const int row = mt*16 + (l >> 4)*4 + reg;
      const int srow = sl[row];
      #pragma unroll
      for (int nt = 0; nt < 3; nt++) {
        const int col = wv*48 + nt*16 + (l & 15);
        float vvv = acc[mt][nt][reg];
        if (col >= 128) vvv += b_beta[c*64 + (col - 128)];
        kvsel[(size_t)srow*192 + col] = vvv;
      }
    }
  }
}

// ---------------- dense fp32 SGEMM for q (unchanged) -------------------------
__global__ __launch_bounds__(256) void sgemm_kernel(
    const float* __restrict__ A, const float* __restrict__ B,
    float* __restrict__ C, int N, int K)
{
  __shared__ __align__(16) float As[16][68];
  __shared__ __align__(16) float Bs[16][68];
  const int tid = threadIdx.x;
  const int tx = tid & 15, ty = tid >> 4;
  const int m0 = blockIdx.x << 6, n0 = blockIdx.y << 6;
  const int lr = tid >> 2, lk = (tid & 3) << 2;
  float acc[4][4] = {{0.f,0.f,0.f,0.f},{0.f,0.f,0.f,0.f},
                     {0.f,0.f,0.f,0.f},{0.f,0.f,0.f,0.f}};
  for (int k0 = 0; k0 < K; k0 += 16) {
    float4 a = *(const float4*)&A[(size_t)(m0+lr)*K + k0 + lk];
    float4 b = *(const float4*)&B[(size_t)(n0+lr)*K + k0 + lk];
    As[lk+0][lr]=a.x; As[lk+1][lr]=a.y; As[lk+2][lr]=a.z; As[lk+3][lr]=a.w;
    Bs[lk+0][lr]=b.x; Bs[lk+1][lr]=b.y; Bs[lk+2][lr]=b.z; Bs[lk+3][lr]=b.w;
    __syncthreads();
    #pragma unroll
    for (int kk = 0; kk < 16; kk++) {
      float4 av = *(const float4*)&As[kk][ty<<2];
      float4 bv = *(const float4*)&Bs[kk][tx<<2];
      acc[0][0] += av.x*bv.x; acc[0][1] += av.x*bv.y; acc[0][2] += av.x*bv.z; acc[0][3] += av.x*bv.w;
      acc[1][0] += av.y*bv.x; acc[1][1] += av.y*bv.y; acc[1][2] += av.y*bv.z; acc[1][3] += av.y*bv.w;
      acc[2][0] += av.z*bv.x; acc[2][1] += av.z*bv.y; acc[2][2] += av.z*bv.z; acc[2][3] += av.z*bv.w;
      acc[3][0] += av.w*bv.x; acc[3][1] += av.w*bv.y; acc[3][2] += av.w*bv.z; acc[3][3] += av.w*bv.w;
    }
    __syncthreads();
  }
  #pragma unroll
  for (int u = 0; u < 4; u++)
    *(float4*)&C[(size_t)(m0 + (ty<<2) + u)*N + n0 + (tx<<2)] =
        make_float4(acc[u][0], acc[u][1], acc[u][2], acc[u][3]);
}

// ---------------- recurrence: 4 waves per (b,c) task -------------------------
// v5: block = 1 task = 4 waves (256 thr), grid = 1024 -> 4 blocks/CU ->
// 4 waves/SIMD (v4 was 2). Wave h owns S-rows h*16..h*16+15; lane
// (jq=l>>4, rl=l&15) owns 16 S elems. Dots = 16 FMA + shfl_xor(16)+(32).
// ldsO slots have a single writer -> plain stores, no atomics, no zero-init;
// barriers only around the per-64-step flush.
__global__ __launch_bounds__(256) void recur_kernel(
    const int* __restrict__ selp,     // [TOK] m1|m2<<8
    const float* __restrict__ w,      // [TOK][16]
    const float* __restrict__ kvsel,  // [SELROWS][192]
    const float* __restrict__ qb,     // [TOK][64]
    float* __restrict__ out,          // [TOK][64] accum (pre-zeroed)
    float* __restrict__ Sfin)         // [B][16][64][64]
{
  const int wv = threadIdx.x >> 6, lane = threadIdx.x & 63;
  const int task = blockIdx.x, b = task >> 4, c = task & 15;
  const int rl = lane & 15, jq = lane >> 4;      // row-in-wave, j-quarter
  const int row = wv*16 + rl;                    // S row this lane owns
  __shared__ __align__(16) float ldsQ[4][2][64];
  __shared__ __align__(16) float ldsK[4][2][64];
  __shared__ __align__(16) float ldsO[64][64];   // 16 KB output window

  float S[16];                                   // S[row][jq*16 + 0..15]
  #pragma unroll
  for (int j = 0; j < 16; j++) S[j] = 0.f;

  const int*   sp = selp + b;                        // stride 64 per t
  const float* wp = w  + (size_t)b*NB + c;           // stride 1024 per t
  const float* qp = qb + (size_t)b*NS + lane;        // staging (lane = j)
  float*       op = out + (size_t)b*NS + lane;       // flush (lane = outdim)

  // ---- selp chunk buffers (chunked loads + readlane; no per-step drain) ----
  int svA = sp[(size_t)(lane)*64];
  int svB = sp[(size_t)(64 + lane)*64];
  auto PICKSEL = [&](int tti) -> int {
    int v = ((tti >> 6) & 1) ? svB : svA;
    return __builtin_amdgcn_readlane(v, tti & 63);
  };

  float kk[4], vf[4], bf_[4], qq[4], wc[4], bet[2];

  #pragma unroll
  for (int i = 0; i < 3; i++) {
    qq[i] = qp[(size_t)i*4096];
    wc[i] = wp[(size_t)i*1024];
    kk[i] = vf[i] = bf_[i] = 0.f;
    const int mm = PICKSEL(i);
    if (c == (mm & 255) || c == (mm >> 8)) {
      const float* r = kvsel + ((size_t)2*(i*BATCH + b) + ((c == (mm >> 8)) ? 1 : 0))*192;
      kk[i]  = r[lane];        // j-indexed (for norm + stage)
      vf[i]  = r[64 + row];    // row-indexed
      bf_[i] = r[128 + row];   // row-indexed
    }
  }
  bet[0] = bet[1] = 0.f;
  ldsQ[wv][0][lane] = qq[0];
  {
    const int mm = PICKSEL(0);
    if (c == (mm & 255) || c == (mm >> 8)) {
      float s2 = kk[0]*kk[0];
      #pragma unroll
      for (int o = 32; o; o >>= 1) s2 += __shfl_xor(s2, o);
      ldsK[wv][0][lane] = kk[0]*__builtin_amdgcn_rcpf(sqrtf(s2) + 1e-6f);
      bet[0] = sigm(bf_[0]);
    }
  }

  #pragma unroll 2
  for (int t = 0; t < T_STEPS; t++) {
    const int i0 = t & 3, i1 = (t+1) & 3, i3 = (t+3) & 3;
    // ---- refill sel chunk --------------------------------------------------
    if ((t & 63) == 0 && t) {
      const int nc = (t >> 6) + 1;
      int nv = sp[(size_t)(nc*64 + lane)*64];
      if (nc & 1) svB = nv; else svA = nv;
    }
    // ---- prefetch data t+3 -------------------------------------------------
    qq[i3] = qp[(size_t)(t+3)*4096];
    wc[i3] = wp[(size_t)(t+3)*1024];
    {
      const int mm = PICKSEL(t+3);
      kk[i3] = vf[i3] = bf_[i3] = 0.f;
      if (c == (mm & 255) || c == (mm >> 8)) {
        const float* r = kvsel + ((size_t)2*((t+3)*BATCH + b) + ((c == (mm >> 8)) ? 1 : 0))*192;
        kk[i3]  = r[lane];
        vf[i3]  = r[64 + row];
        bf_[i3] = r[128 + row];
      }
    }
    // ---- stage t+1 ---------------------------------------------------------
    ldsQ[wv][(t+1) & 1][lane] = qq[i1];
    {
      const int mm = PICKSEL(t+1);
      if (c == (mm & 255) || c == (mm >> 8)) {
        float s2 = kk[i1]*kk[i1];
        #pragma unroll
        for (int o = 32; o; o >>= 1) s2 += __shfl_xor(s2, o);
        ldsK[wv][(t+1) & 1][lane] = kk[i1]*__builtin_amdgcn_rcpf(sqrtf(s2) + 1e-6f);
        bet[(t+1) & 1] = sigm(bf_[i1]);
      }
    }
    // ---- compute step t (16 elems/lane + 2 shfl) ---------------------------
    {
      const int mm = PICKSEL(t);
      if (c == (mm & 255) || c == (mm >> 8)) {
        const float* kr = &ldsK[wv][t & 1][jq << 4];
        float aa[4] = {0.f, 0.f, 0.f, 0.f};
        #pragma unroll
        for (int j = 0; j < 16; j += 4) {
          float4 k4 = *(const float4*)&kr[j];
          const int ai = j >> 2;
          aa[ai] = fmaf(S[j+3], k4.w, fmaf(S[j+2], k4.z,
                   fmaf(S[j+1], k4.y, fmaf(S[j+0], k4.x, aa[ai]))));
        }
        float r = (aa[0] + aa[1]) + (aa[2] + aa[3]);
        r += __shfl_xor(r, 16);                     // combine j-quarters
        r += __shfl_xor(r, 32);
        const float g = vf[i0] - r;
        const float be = bet[t & 1];
        #pragma unroll
        for (int j = 0; j < 16; j += 4) {
          float4 k4 = *(const float4*)&kr[j];
          S[j+0] = fast_tanh(fmaf(be, S[j+0], g*k4.x));
          S[j+1] = fast_tanh(fmaf(be, S[j+1], g*k4.y));
          S[j+2] = fast_tanh(fmaf(be, S[j+2], g*k4.z));
          S[j+3] = fast_tanh(fmaf(be, S[j+3], g*k4.w));
        }
      }
    }
    // ---- output: Sq, silu-gate, single-writer LDS store --------------------
    {
      const float* qr = &ldsQ[wv][t & 1][jq << 4];
      float aa[4] = {0.f, 0.f, 0.f, 0.f};
      #pragma unroll
      for (int j = 0; j < 16; j += 4) {
        float4 q4 = *(const float4*)&qr[j];
        const int ai = j >> 2;
        aa[ai] = fmaf(S[j+3], q4.w, fmaf(S[j+2], q4.z,
                 fmaf(S[j+1], q4.y, fmaf(S[j+0], q4.x, aa[ai]))));
      }
      float sq = (aa[0] + aa[1]) + (aa[2] + aa[3]);
      sq += __shfl_xor(sq, 16);                     // combine j-quarters
      sq += __shfl_xor(sq, 32);
      const float bo = sq*sq*sigm(sq);
      if (jq == 0)
        ldsO[t & 63][row] = wc[i0]*bo;              // single writer per slot
    }
    // ---- window flush every 64 steps ---------------------------------------
    if ((t & 63) == 63) {
      __syncthreads();
      const int t0 = t & ~63;
      #pragma unroll
      for (int r = 0; r < 16; r++) {
        const int s = (wv<<4) + r;                  // wave flushes 16 steps
        unsafeAtomicAdd(&op[(size_t)(t0 + s)*4096], ldsO[s][lane]);
      }
      __syncthreads();
    }
  }

  // Sfin: lane writes its 16 j's of its row
  float* dst = Sfin + (((size_t)b*NB + c)*NS + row)*NS + (jq << 4);
  #pragma unroll
  for (int j = 0; j < 16; j += 4)
    *(float4*)&dst[j] = make_float4(S[j], S[j+1], S[j+2], S[j+3]);
}

extern "C" void kernel_launch(void* const* d_in, const int* in_sizes, int n_in,
                              void* d_out, int out_size, void* d_ws, size_t ws_size,
                              hipStream_t stream) {
  const float* x        = (const float*)d_in[0];
  const float* W_router = (const float*)d_in[1];
  const float* W_kv     = (const float*)d_in[2];
  const float* W_beta   = (const float*)d_in[3];
  const float* b_beta   = (const float*)d_in[4];
  const float* W_q      = (const float*)d_in[5];

  float* out  = (float*)d_out;
  float* Sfin = out + (size_t)TOK*NS;
  float* ws     = (float*)d_ws;
  float* logits = ws + WS_LOGITS;
  float* wsm    = ws + WS_W;
  float* qb     = ws + WS_Q;
  int*   selp   = (int*)(ws + WS_SEL);
  int*   toklist= (int*)(ws + WS_TOKL);
  int*   sellist= (int*)(ws + WS_SELL);
  int*   cnt    = (int*)(ws + WS_CNT);
  int*   tile   = (int*)(ws + WS_TILE);
  float* kvsel  = ws + WS_KVSEL;
  short* Whi    = (short*)(ws + WS_WHI);
  short* Wlo    = (short*)(ws + WS_WLO);

  hipMemsetAsync(out, 0, (size_t)TOK*NS*sizeof(float), stream);
  hipMemsetAsync(cnt, 0, 16*sizeof(int), stream);

  logits_kernel<<<TOK/64, 256, 0, stream>>>(x, W_router, logits);
  sgemm_kernel<<<dim3(TOK/64, 1), 256, 0, stream>>>(x, W_q, qb, NS, DIM);
  wcast_kernel<<<NB*192, 256, 0, stream>>>(W_kv, W_beta, Whi, Wlo);
  route_kernel<<<TOK/256, 256, 0, stream>>>(logits, wsm, selp, toklist, sellist, cnt);
  prefix_kernel<<<1, 256, 0, stream>>>(cnt, tile, toklist, sellist);
  gather_gemm_kernel<<<MAXTILES, 256, 0, stream>>>(
      x, Whi, Wlo, b_beta, tile, toklist, sellist, kvsel);
  recur_kernel<<<BATCH*NB, 256, 0, stream>>>(selp, wsm, kvsel, qb, out, Sfin);
}

// Round 8
// 1133.590 us; speedup vs baseline: 1.0961x; 1.0961x over previous
//
#include <hip/hip_runtime.h>
#include <hip/hip_bf16.h>
#include <math.h>

#define T_STEPS 512
#define BATCH   64
#define DIM     1024
#define NB      16
#define NS      64
#define TOK     (T_STEPS*BATCH)        // 32768
#define SELROWS (2*TOK + NB*64)        // 66560 (spare rows for tile padding)
#define MAXTILES ((2*TOK)/64 + NB)     // 1040

// ---- workspace layout (float offsets) ----
#define WS_LOGITS 0                        // TOK*16
#define WS_W      (WS_LOGITS + TOK*NB)     // TOK*16 softmax weights
#define WS_Q      (WS_W + TOK*NB)          // TOK*64
#define WS_SEL    (WS_Q + TOK*NS)          // TOK ints (m1|m2<<8)
#define WS_TOKL   (WS_SEL + TOK)           // NB*TOK ints
#define WS_SELL   (WS_TOKL + NB*TOK)       // NB*TOK ints
#define WS_CNT    (WS_SELL + NB*TOK)       // 16 ints
#define WS_TILE   (WS_CNT + 16)            // 32 ints
#define WS_KVSEL  (WS_TILE + 32)           // SELROWS*192 floats
#define WS_WHI    (WS_KVSEL + SELROWS*192) // bf16 weights
#define WS_WLO    (WS_WHI + (NB*192*DIM)/2)

typedef __attribute__((ext_vector_type(8))) short short8x;
typedef __attribute__((ext_vector_type(4))) float f32x4;

__device__ __forceinline__ short f2bf_hi(float f, float& rem) {
  __hip_bfloat16 h = __float2bfloat16(f);
  rem = f - __bfloat162float(h);
  return *(short*)&h;
}
__device__ __forceinline__ short f2bf(float f) {
  __hip_bfloat16 h = __float2bfloat16(f);
  return *(short*)&h;
}
__device__ __forceinline__ float sigm(float x) {
  return __builtin_amdgcn_rcpf(1.f + __builtin_amdgcn_exp2f(-1.4426950408889634f*x));
}
__device__ __forceinline__ float fast_tanh(float v) {
  v = fminf(10.f, fmaxf(-10.f, v));
  float e = __builtin_amdgcn_exp2f(2.8853900817779268f*v);
  return 1.f - 2.f*__builtin_amdgcn_rcpf(e + 1.f);
}

// ---------------- router logits (unchanged) ---------------------------------
__global__ __launch_bounds__(256) void logits_kernel(
    const float* __restrict__ x, const float* __restrict__ Wr,
    float* __restrict__ logits)
{
  const int wv   = __builtin_amdgcn_readfirstlane(threadIdx.x >> 6);
  const int lane = threadIdx.x & 63;
  const int tok  = blockIdx.x*64 + lane;
  const float* xr = x + (size_t)tok*DIM;
  const float* w0 = Wr + (size_t)(4*wv)*DIM;
  double acc[4] = {0.0, 0.0, 0.0, 0.0};
  for (int k0 = 0; k0 < DIM; k0 += 32) {
    float4 xv[8];
    #pragma unroll
    for (int i = 0; i < 8; i++) xv[i] = *(const float4*)&xr[k0 + 4*i];
    #pragma unroll
    for (int cc = 0; cc < 4; cc++) {
      const float* wr = w0 + (size_t)cc*DIM + k0;
      double s = 0.0;
      #pragma unroll
      for (int i = 0; i < 8; i++) {
        float4 w4 = *(const float4*)&wr[4*i];
        s += ((double)xv[i].x*(double)w4.x + (double)xv[i].y*(double)w4.y)
           + ((double)xv[i].z*(double)w4.z + (double)xv[i].w*(double)w4.w);
      }
      acc[cc] += s;
    }
  }
  #pragma unroll
  for (int cc = 0; cc < 4; cc++)
    logits[(size_t)tok*NB + 4*wv + cc] = (float)acc[cc];
}

// ---------------- routing (unchanged) ---------------------------------------
__global__ __launch_bounds__(256) void route_kernel(
    const float* __restrict__ logits, float* __restrict__ w,
    int* __restrict__ selp, int* __restrict__ toklist,
    int* __restrict__ sellist, int* __restrict__ cnt)
{
  const int tok = blockIdx.x*256 + threadIdx.x;
  const float* lg = logits + (size_t)tok*NB;
  float lv[NB];
  #pragma unroll
  for (int l = 0; l < NB; l++) lv[l] = lg[l];
  float v1 = lv[0]; int m1 = 0;
  #pragma unroll
  for (int l = 1; l < NB; l++) if (lv[l] > v1) { v1 = lv[l]; m1 = l; }
  float v2 = -3.4e38f; int m2 = 0;
  #pragma unroll
  for (int l = 0; l < NB; l++) if (l != m1 && lv[l] > v2) { v2 = lv[l]; m2 = l; }
  float ev[NB], sum = 0.f;
  #pragma unroll
  for (int l = 0; l < NB; l++) { ev[l] = __expf(lv[l] - v1); sum += ev[l]; }
  const float rs = __builtin_amdgcn_rcpf(sum);
  #pragma unroll
  for (int l = 0; l < NB; l++) w[(size_t)tok*NB + l] = ev[l] * rs;
  selp[tok] = m1 | (m2 << 8);
  int p1 = atomicAdd(&cnt[m1], 1);
  toklist[m1*TOK + p1] = tok;  sellist[m1*TOK + p1] = 2*tok;
  int p2 = atomicAdd(&cnt[m2], 1);
  toklist[m2*TOK + p2] = tok;  sellist[m2*TOK + p2] = 2*tok + 1;
}

// ---------------- tile prefix + pad tail tiles (unchanged) -------------------
__global__ void prefix_kernel(const int* __restrict__ cnt, int* __restrict__ tile,
                              int* __restrict__ toklist, int* __restrict__ sellist)
{
  __shared__ int off[NB+1];
  if (threadIdx.x == 0) {
    int a = 0;
    for (int c = 0; c < NB; c++) { off[c] = a; tile[c] = a; a += (cnt[c] + 63) >> 6; }
    off[NB] = a; tile[NB] = a;
  }
  __syncthreads();
  for (int c = 0; c < NB; c++) {
    const int s = cnt[c], e = (off[c+1] - off[c]) << 6;
    for (int i = s + threadIdx.x; i < e; i += 256) {
      toklist[c*TOK + i] = 0;
      sellist[c*TOK + i] = 2*TOK + c*64 + (i & 63);
    }
  }
}

// ---------------- W split-cast (unchanged) -----------------------------------
__global__ void wcast_kernel(const float* __restrict__ Wkv,
                             const float* __restrict__ Wb,
                             short* __restrict__ Whi, short* __restrict__ Wlo)
{
  const int R = blockIdx.x, c = R/192, r = R%192;
  const float* src = (r < 128) ? Wkv + ((size_t)c*128 + r)*DIM
                               : Wb  + ((size_t)c*64 + (r-128))*DIM;
  const int k = threadIdx.x*4;
  float4 f = *(const float4*)&src[k];
  float ff[4] = {f.x, f.y, f.z, f.w};
  short* dh = Whi + (size_t)R*DIM + k;
  short* dl = Wlo + (size_t)R*DIM + k;
  #pragma unroll
  for (int e = 0; e < 4; e++) {
    float rem;
    dh[e] = f2bf_hi(ff[e], rem);
    dl[e] = f2bf(rem);
  }
}

// ---------------- gather-GEMM: bf16x3 MFMA (unchanged) ----------------------
__global__ __launch_bounds__(256) void gather_gemm_kernel(
    const float* __restrict__ x,
    const short* __restrict__ Whi, const short* __restrict__ Wlo,
    const float* __restrict__ b_beta,
    const int* __restrict__ tileoff, const int* __restrict__ toklist,
    const int* __restrict__ sellist, float* __restrict__ kvsel)
{
  __shared__ short Ahi[64][40];
  __shared__ short Alo[64][40];
  __shared__ int tl[64], sl[64];
  const int tile = blockIdx.x;
  if (tile >= tileoff[NB]) return;
  int c = 0;
  while (c < NB-1 && tile >= tileoff[c+1]) c++;
  const int ti = tile - tileoff[c];
  const int tid = threadIdx.x;
  if (tid < 64) {
    tl[tid] = toklist[c*TOK + (ti<<6) + tid];
    sl[tid] = sellist[c*TOK + (ti<<6) + tid];
  }
  __syncthreads();

  const int wv = tid >> 6, l = tid & 63;
  const int arow = tid >> 2, akseg = (tid & 3) << 3;
  const float* aptr = x + (size_t)tl[arow]*DIM + akseg;
  const short* bh_p = Whi + ((size_t)c*192 + wv*48 + (l & 15))*DIM + ((l >> 4) << 3);
  const short* bl_p = Wlo + ((size_t)c*192 + wv*48 + (l & 15))*DIM + ((l >> 4) << 3);

  f32x4 acc[4][3];
  #pragma unroll
  for (int mt = 0; mt < 4; mt++)
    #pragma unroll
    for (int nt = 0; nt < 3; nt++) acc[mt][nt] = (f32x4){0.f,0.f,0.f,0.f};

  float4 af[2][2];
  short8x bh[2][3], bl[2][3];
  af[0][0] = *(const float4*)&aptr[0];
  af[0][1] = *(const float4*)&aptr[4];
  #pragma unroll
  for (int nt = 0; nt < 3; nt++) {
    bh[0][nt] = *(const short8x*)&bh_p[nt*16*DIM];
    bl[0][nt] = *(const short8x*)&bl_p[nt*16*DIM];
  }

  #pragma unroll 2
  for (int ch = 0; ch < 32; ch++) {
    const int p = ch & 1, pn = p ^ 1;
    {
      float f8[8] = {af[p][0].x, af[p][0].y, af[p][0].z, af[p][0].w,
                     af[p][1].x, af[p][1].y, af[p][1].z, af[p][1].w};
      short h8[8], l8[8];
      #pragma unroll
      for (int e = 0; e < 8; e++) {
        float rem;
        h8[e] = f2bf_hi(f8[e], rem);
        l8[e] = f2bf(rem);
      }
      *(short8x*)&Ahi[arow][akseg] = *(short8x*)h8;
      *(short8x*)&Alo[arow][akseg] = *(short8x*)l8;
    }
    if (ch < 31) {
      af[pn][0] = *(const float4*)&aptr[(ch+1)*32];
      af[pn][1] = *(const float4*)&aptr[(ch+1)*32 + 4];
    }
    __syncthreads();
    if (ch < 31) {
      #pragma unroll
      for (int nt = 0; nt < 3; nt++) {
        bh[pn][nt] = *(const short8x*)&bh_p[nt*16*DIM + (ch+1)*32];
        bl[pn][nt] = *(const short8x*)&bl_p[nt*16*DIM + (ch+1)*32];
      }
    }
    short8x ah[4], al[4];
    #pragma unroll
    for (int mt = 0; mt < 4; mt++) {
      ah[mt] = *(const short8x*)&Ahi[mt*16 + (l & 15)][(l >> 4) << 3];
      al[mt] = *(const short8x*)&Alo[mt*16 + (l & 15)][(l >> 4) << 3];
    }
    #pragma unroll
    for (int mt = 0; mt < 4; mt++)
      #pragma unroll
      for (int nt = 0; nt < 3; nt++) {
        acc[mt][nt] = __builtin_amdgcn_mfma_f32_16x16x32_bf16(ah[mt], bh[p][nt], acc[mt][nt], 0, 0, 0);
        acc[mt][nt] = __builtin_amdgcn_mfma_f32_16x16x32_bf16(ah[mt], bl[p][nt], acc[mt][nt], 0, 0, 0);
        acc[mt][nt] = __builtin_amdgcn_mfma_f32_16x16x32_bf16(al[mt], bh[p][nt], acc[mt][nt], 0, 0, 0);
      }
    __syncthreads();
  }

  #pragma unroll
  for (int mt = 0; mt < 4; mt++) {
    #pragma unroll
    for (int reg = 0; reg < 4; reg++) {
      const int row = mt*16 + (l >> 4)*4 + reg;
      const int srow = sl[row];
      #pragma unroll
      for (int nt = 0; nt < 3; nt++) {
        const int col = wv*48 + nt*16 + (l & 15);
        float vvv = acc[mt][nt][reg];
        if (col >= 128) vvv += b_beta[c*64 + (col - 128)];
        kvsel[(size_t)srow*192 + col] = vvv;
      }
    }
  }
}

// ---------------- dense fp32 SGEMM for q (unchanged) -------------------------
__global__ __launch_bounds__(256) void sgemm_kernel(
    const float* __restrict__ A, const float* __restrict__ B,
    float* __restrict__ C, int N, int K)
{
  __shared__ __align__(16) float As[16][68];
  __shared__ __align__(16) float Bs[16][68];
  const int tid = threadIdx.x;
  const int tx = tid & 15, ty = tid >> 4;
  const int m0 = blockIdx.x << 6, n0 = blockIdx.y << 6;
  const int lr = tid >> 2, lk = (tid & 3) << 2;
  float acc[4][4] = {{0.f,0.f,0.f,0.f},{0.f,0.f,0.f,0.f},
                     {0.f,0.f,0.f,0.f},{0.f,0.f,0.f,0.f}};
  for (int k0 = 0; k0 < K; k0 += 16) {
    float4 a = *(const float4*)&A[(size_t)(m0+lr)*K + k0 + lk];
    float4 b = *(const float4*)&B[(size_t)(n0+lr)*K + k0 + lk];
    As[lk+0][lr]=a.x; As[lk+1][lr]=a.y; As[lk+2][lr]=a.z; As[lk+3][lr]=a.w;
    Bs[lk+0][lr]=b.x; Bs[lk+1][lr]=b.y; Bs[lk+2][lr]=b.z; Bs[lk+3][lr]=b.w;
    __syncthreads();
    #pragma unroll
    for (int kk = 0; kk < 16; kk++) {
      float4 av = *(const float4*)&As[kk][ty<<2];
      float4 bv = *(const float4*)&Bs[kk][tx<<2];
      acc[0][0] += av.x*bv.x; acc[0][1] += av.x*bv.y; acc[0][2] += av.x*bv.z; acc[0][3] += av.x*bv.w;
      acc[1][0] += av.y*bv.x; acc[1][1] += av.y*bv.y; acc[1][2] += av.y*bv.z; acc[1][3] += av.y*bv.w;
      acc[2][0] += av.z*bv.x; acc[2][1] += av.z*bv.y; acc[2][2] += av.z*bv.z; acc[2][3] += av.z*bv.w;
      acc[3][0] += av.w*bv.x; acc[3][1] += av.w*bv.y; acc[3][2] += av.w*bv.z; acc[3][3] += av.w*bv.w;
    }
    __syncthreads();
  }
  #pragma unroll
  for (int u = 0; u < 4; u++)
    *(float4*)&C[(size_t)(m0 + (ty<<2) + u)*N + n0 + (tx<<2)] =
        make_float4(acc[u][0], acc[u][1], acc[u][2], acc[u][3]);
}

// ---------------- recurrence v7: v4 structure + ballot masks + w-chunks ------
// Geometry = v4 (PROVEN, 543us): 256 blocks x 512 thr, 4 tasks/block (same b),
// 2 waves/task; wave h owns S-rows h*32..h*32+31; lane (rl=l&31, jh=l>>5)
// owns 32 S elems; dots = 32 FMA + shfl_xor(32). Diet changes only:
//  (1) per-64-step ballot masks (selected / is-m2) replace PICKSEL readlane
//      chains; per-step tests are uniform shift+and (SALU).
//  (2) w via chunk registers + __shfl broadcast (1 load/64 steps, was 1/step).
//  (3) q pointer-bump.
__global__ __launch_bounds__(512, 1) void recur_kernel(
    const int* __restrict__ selp,     // [TOK] m1|m2<<8
    const float* __restrict__ w,      // [TOK][16]
    const float* __restrict__ kvsel,  // [SELROWS][192]
    const float* __restrict__ qb,     // [TOK][64]
    float* __restrict__ out,          // [TOK][64] accum (pre-zeroed)
    float* __restrict__ Sfin)         // [B][16][64][64]
{
  const int wv = threadIdx.x >> 6, lane = threadIdx.x & 63;
  const int tt = wv >> 1, h = wv & 1;            // task-in-block, row-half
  const int task = blockIdx.x*4 + tt, b = task >> 4, c = task & 15;
  const int rl = lane & 31, jh = lane >> 5;      // row-in-half, j-half
  const int row = h*32 + rl;                     // S row this lane owns
  __shared__ __align__(16) float ldsQ[8][2][64];
  __shared__ __align__(16) float ldsK[8][2][64];
  __shared__ __align__(16) float ldsO[64][64];   // 16 KB output window (same b)

  float S[32];                                   // S[row][jh*32 + 0..31]
  #pragma unroll
  for (int j = 0; j < 32; j++) S[j] = 0.f;

  const int*   sp = selp + b;                    // stride 64 per t
  const float* wp = w  + (size_t)b*NB + c;       // stride 1024 per t
  const float* qp = qb + (size_t)b*NS + lane;    // staging (lane = j)
  float*       op = out + (size_t)b*NS + lane;   // flush (lane = outdim)

  // zero output window: 8 rows per wave
  #pragma unroll
  for (int r = 0; r < 8; r++) ldsO[(wv<<3) + r][lane] = 0.f;

  // ---- per-chunk ballot masks: bit L of chunk = step ch*64+L ---------------
  unsigned long long selA, selB, slotA, slotB;
  {
    int nv0 = sp[(size_t)lane*64];
    int nv1 = sp[(size_t)(64 + lane)*64];
    bool p2a = (c == (nv0 >> 8)), pa = (c == (nv0 & 255)) || p2a;
    bool p2b = (c == (nv1 >> 8)), pb = (c == (nv1 & 255)) || p2b;
    selA = __ballot(pa);  slotA = __ballot(p2a);
    selB = __ballot(pb);  slotB = __ballot(p2b);
  }
  auto SEL = [&](int tti) -> bool {
    const unsigned long long m = ((tti >> 6) & 1) ? selB : selA;
    return (m >> (tti & 63)) & 1ull;
  };
  auto SLOT = [&](int tti) -> int {
    const unsigned long long m = ((tti >> 6) & 1) ? slotB : slotA;
    return (int)((m >> (tti & 63)) & 1ull);
  };

  // ---- w chunks (lane L of chunk ch holds w[(ch*64+L), c]) -----------------
  float wA = wp[(size_t)lane*1024];
  float wB = wp[(size_t)(64 + lane)*1024];

  float kk[4], vf[4], bf_[4], qq[4], bet[2];

  #pragma unroll
  for (int i = 0; i < 3; i++) {
    qq[i] = qp[(size_t)i*4096];
    if (SEL(i)) {
      const float* r = kvsel + ((size_t)2*(i*BATCH + b) + SLOT(i))*192;
      kk[i]  = r[lane];        // j-indexed (for norm + stage)
      vf[i]  = r[64 + row];    // row-indexed
      bf_[i] = r[128 + row];   // row-indexed
    }
  }
  bet[0] = bet[1] = 0.f;
  ldsQ[wv][0][lane] = qq[0];
  if (selA & 1ull) {
    float s2 = kk[0]*kk[0];
    #pragma unroll
    for (int o = 32; o; o >>= 1) s2 += __shfl_xor(s2, o);
    ldsK[wv][0][lane] = kk[0]*__builtin_amdgcn_rcpf(sqrtf(s2) + 1e-6f);
    bet[0] = sigm(bf_[0]);
  }
  const float* qpp = qp + (size_t)3*4096;
  __syncthreads();   // ldsO zeroed before any ds_add

  #pragma unroll 2
  for (int t = 0; t < T_STEPS; t++) {
    const int i0 = t & 3, i1 = (t+1) & 3, i3 = (t+3) & 3;
    // ---- chunk refill: sel/slot masks + w, 61+ steps before first use ------
    if ((t & 63) == 0 && t) {
      const int nc = (t >> 6) + 1;
      int nv = sp[(size_t)(nc*64 + lane)*64];
      float nw = wp[(size_t)(nc*64 + lane)*1024];
      bool p2 = (c == (nv >> 8)), pr = (c == (nv & 255)) || p2;
      unsigned long long ms = __ballot(pr), m2 = __ballot(p2);
      if (nc & 1) { selB = ms; slotB = m2; wB = nw; }
      else        { selA = ms; slotA = m2; wA = nw; }
    }
    // ---- prefetch data t+3 -------------------------------------------------
    qq[i3] = *qpp; qpp += 4096;
    if (SEL(t+3)) {
      const float* r = kvsel + ((size_t)2*((t+3)*BATCH + b) + SLOT(t+3))*192;
      kk[i3]  = r[lane];
      vf[i3]  = r[64 + row];
      bf_[i3] = r[128 + row];
    }
    // ---- stage t+1 (k loaded 2 iters ago: norm off critical path) ----------
    ldsQ[wv][(t+1) & 1][lane] = qq[i1];
    if (SEL(t+1)) {
      float s2 = kk[i1]*kk[i1];
      #pragma unroll
      for (int o = 32; o; o >>= 1) s2 += __shfl_xor(s2, o);
      ldsK[wv][(t+1) & 1][lane] = kk[i1]*__builtin_amdgcn_rcpf(sqrtf(s2) + 1e-6f);
      bet[(t+1) & 1] = sigm(bf_[i1]);
    }
    // ---- compute step t (32 elems/lane + 1 shfl) ---------------------------
    if (SEL(t)) {
      const float* kr = &ldsK[wv][t & 1][jh << 5];
      float aa[4] = {0.f, 0.f, 0.f, 0.f};
      #pragma unroll
      for (int j = 0; j < 32; j += 4) {
        float4 k4 = *(const float4*)&kr[j];
        const int ai = (j >> 2) & 3;
        aa[ai] = fmaf(S[j+3], k4.w, fmaf(S[j+2], k4.z,
                 fmaf(S[j+1], k4.y, fmaf(S[j+0], k4.x, aa[ai]))));
      }
      float r = (aa[0] + aa[1]) + (aa[2] + aa[3]);
      r += __shfl_xor(r, 32);                     // combine j-halves
      const float g = vf[i0] - r;
      const float be = bet[t & 1];
      #pragma unroll
      for (int j = 0; j < 32; j += 4) {
        float4 k4 = *(const float4*)&kr[j];
        S[j+0] = fast_tanh(fmaf(be, S[j+0], g*k4.x));
        S[j+1] = fast_tanh(fmaf(be, S[j+1], g*k4.y));
        S[j+2] = fast_tanh(fmaf(be, S[j+2], g*k4.z));
        S[j+3] = fast_tanh(fmaf(be, S[j+3], g*k4.w));
      }
    }
    // ---- output: Sq, silu-gate, LDS-window accumulate ----------------------
    {
      const float* qr = &ldsQ[wv][t & 1][jh << 5];
      float aa[4] = {0.f, 0.f, 0.f, 0.f};
      #pragma unroll
      for (int j = 0; j < 32; j += 4) {
        float4 q4 = *(const float4*)&qr[j];
        const int ai = (j >> 2) & 3;
        aa[ai] = fmaf(S[j+3], q4.w, fmaf(S[j+2], q4.z,
                 fmaf(S[j+1], q4.y, fmaf(S[j+0], q4.x, aa[ai]))));
      }
      float sq = (aa[0] + aa[1]) + (aa[2] + aa[3]);
      sq += __shfl_xor(sq, 32);                   // combine j-halves
      const float bo = sq*sq*sigm(sq);
      const float wcur = __shfl(((t >> 6) & 1) ? wB : wA, t & 63);
      if (jh == 0)
        unsafeAtomicAdd(&ldsO[t & 63][row], wcur*bo);
    }
    // ---- window flush every 64 steps ---------------------------------------
    if ((t & 63) == 63) {
      __syncthreads();
      const int t0 = t & ~63;
      #pragma unroll
      for (int r = 0; r < 8; r++) {
        const int wrow = (wv<<3) + r;
        unsafeAtomicAdd(&op[(size_t)(t0 + wrow)*4096], ldsO[wrow][lane]);
        ldsO[wrow][lane] = 0.f;
      }
      __syncthreads();
    }
  }

  // Sfin: lane writes its 32 j's of its row
  float* dst = Sfin + (((size_t)b*NB + c)*NS + row)*NS + (jh << 5);
  #pragma unroll
  for (int j = 0; j < 32; j += 4)
    *(float4*)&dst[j] = make_float4(S[j], S[j+1], S[j+2], S[j+3]);
}

extern "C" void kernel_launch(void* const* d_in, const int* in_sizes, int n_in,
                              void* d_out, int out_size, void* d_ws, size_t ws_size,
                              hipStream_t stream) {
  const float* x        = (const float*)d_in[0];
  const float* W_router = (const float*)d_in[1];
  const float* W_kv     = (const float*)d_in[2];
  const float* W_beta   = (const float*)d_in[3];
  const float* b_beta   = (const float*)d_in[4];
  const float* W_q      = (const float*)d_in[5];

  float* out  = (float*)d_out;
  float* Sfin = out + (size_t)TOK*NS;
  float* ws     = (float*)d_ws;
  float* logits = ws + WS_LOGITS;
  float* wsm    = ws + WS_W;
  float* qb     = ws + WS_Q;
  int*   selp   = (int*)(ws + WS_SEL);
  int*   toklist= (int*)(ws + WS_TOKL);
  int*   sellist= (int*)(ws + WS_SELL);
  int*   cnt    = (int*)(ws + WS_CNT);
  int*   tile   = (int*)(ws + WS_TILE);
  float* kvsel  = ws + WS_KVSEL;
  short* Whi    = (short*)(ws + WS_WHI);
  short* Wlo    = (short*)(ws + WS_WLO);

  hipMemsetAsync(out, 0, (size_t)TOK*NS*sizeof(float), stream);
  hipMemsetAsync(cnt, 0, 16*sizeof(int), stream);

  logits_kernel<<<TOK/64, 256, 0, stream>>>(x, W_router, logits);
  sgemm_kernel<<<dim3(TOK/64, 1), 256, 0, stream>>>(x, W_q, qb, NS, DIM);
  wcast_kernel<<<NB*192, 256, 0, stream>>>(W_kv, W_beta, Whi, Wlo);
  route_kernel<<<TOK/256, 256, 0, stream>>>(logits, wsm, selp, toklist, sellist, cnt);
  prefix_kernel<<<1, 256, 0, stream>>>(cnt, tile, toklist, sellist);
  gather_gemm_kernel<<<MAXTILES, 256, 0, stream>>>(
      x, Whi, Wlo, b_beta, tile, toklist, sellist, kvsel);
  recur_kernel<<<(BATCH*NB)/4, 512, 0, stream>>>(selp, wsm, kvsel, qb, out, Sfin);
}

// Round 9
// 1128.101 us; speedup vs baseline: 1.1014x; 1.0049x over previous
//
#include <hip/hip_runtime.h>
#include <hip/hip_bf16.h>
#include <math.h>

#define T_STEPS 512
#define BATCH   64
#define DIM     1024
#define NB      16
#define NS      64
#define TOK     (T_STEPS*BATCH)        // 32768
#define SELROWS (2*TOK + NB*64)        // 66560 (spare rows for tile padding)
#define MAXTILES ((2*TOK)/64 + NB)     // 1040

// ---- workspace layout (float offsets) ----
#define WS_LOGITS 0                        // TOK*16
#define WS_W      (WS_LOGITS + TOK*NB)     // TOK*16 softmax weights
#define WS_Q      (WS_W + TOK*NB)          // TOK*64
#define WS_SEL    (WS_Q + TOK*NS)          // TOK ints (m1|m2<<8)
#define WS_TOKL   (WS_SEL + TOK)           // NB*TOK ints
#define WS_SELL   (WS_TOKL + NB*TOK)       // NB*TOK ints
#define WS_CNT    (WS_SELL + NB*TOK)       // 16 ints
#define WS_TILE   (WS_CNT + 16)            // 32 ints
#define WS_KVSEL  (WS_TILE + 32)           // SELROWS*192 floats
#define WS_WHI    (WS_KVSEL + SELROWS*192) // bf16 weights
#define WS_WLO    (WS_WHI + (NB*192*DIM)/2)

typedef __attribute__((ext_vector_type(8))) short short8x;
typedef __attribute__((ext_vector_type(4))) float f32x4;

__device__ __forceinline__ short f2bf_hi(float f, float& rem) {
  __hip_bfloat16 h = __float2bfloat16(f);
  rem = f - __bfloat162float(h);
  return *(short*)&h;
}
__device__ __forceinline__ short f2bf(float f) {
  __hip_bfloat16 h = __float2bfloat16(f);
  return *(short*)&h;
}
__device__ __forceinline__ float sigm(float x) {
  return __builtin_amdgcn_rcpf(1.f + __builtin_amdgcn_exp2f(-1.4426950408889634f*x));
}
__device__ __forceinline__ float fast_tanh(float v) {
  v = fminf(10.f, fmaxf(-10.f, v));
  float e = __builtin_amdgcn_exp2f(2.8853900817779268f*v);
  return 1.f - 2.f*__builtin_amdgcn_rcpf(e + 1.f);
}

// ---------------- router logits (unchanged) ---------------------------------
__global__ __launch_bounds__(256) void logits_kernel(
    const float* __restrict__ x, const float* __restrict__ Wr,
    float* __restrict__ logits)
{
  const int wv   = __builtin_amdgcn_readfirstlane(threadIdx.x >> 6);
  const int lane = threadIdx.x & 63;
  const int tok  = blockIdx.x*64 + lane;
  const float* xr = x + (size_t)tok*DIM;
  const float* w0 = Wr + (size_t)(4*wv)*DIM;
  double acc[4] = {0.0, 0.0, 0.0, 0.0};
  for (int k0 = 0; k0 < DIM; k0 += 32) {
    float4 xv[8];
    #pragma unroll
    for (int i = 0; i < 8; i++) xv[i] = *(const float4*)&xr[k0 + 4*i];
    #pragma unroll
    for (int cc = 0; cc < 4; cc++) {
      const float* wr = w0 + (size_t)cc*DIM + k0;
      double s = 0.0;
      #pragma unroll
      for (int i = 0; i < 8; i++) {
        float4 w4 = *(const float4*)&wr[4*i];
        s += ((double)xv[i].x*(double)w4.x + (double)xv[i].y*(double)w4.y)
           + ((double)xv[i].z*(double)w4.z + (double)xv[i].w*(double)w4.w);
      }
      acc[cc] += s;
    }
  }
  #pragma unroll
  for (int cc = 0; cc < 4; cc++)
    logits[(size_t)tok*NB + 4*wv + cc] = (float)acc[cc];
}

// ---------------- routing (unchanged) ---------------------------------------
__global__ __launch_bounds__(256) void route_kernel(
    const float* __restrict__ logits, float* __restrict__ w,
    int* __restrict__ selp, int* __restrict__ toklist,
    int* __restrict__ sellist, int* __restrict__ cnt)
{
  const int tok = blockIdx.x*256 + threadIdx.x;
  const float* lg = logits + (size_t)tok*NB;
  float lv[NB];
  #pragma unroll
  for (int l = 0; l < NB; l++) lv[l] = lg[l];
  float v1 = lv[0]; int m1 = 0;
  #pragma unroll
  for (int l = 1; l < NB; l++) if (lv[l] > v1) { v1 = lv[l]; m1 = l; }
  float v2 = -3.4e38f; int m2 = 0;
  #pragma unroll
  for (int l = 0; l < NB; l++) if (l != m1 && lv[l] > v2) { v2 = lv[l]; m2 = l; }
  float ev[NB], sum = 0.f;
  #pragma unroll
  for (int l = 0; l < NB; l++) { ev[l] = __expf(lv[l] - v1); sum += ev[l]; }
  const float rs = __builtin_amdgcn_rcpf(sum);
  #pragma unroll
  for (int l = 0; l < NB; l++) w[(size_t)tok*NB + l] = ev[l] * rs;
  selp[tok] = m1 | (m2 << 8);
  int p1 = atomicAdd(&cnt[m1], 1);
  toklist[m1*TOK + p1] = tok;  sellist[m1*TOK + p1] = 2*tok;
  int p2 = atomicAdd(&cnt[m2], 1);
  toklist[m2*TOK + p2] = tok;  sellist[m2*TOK + p2] = 2*tok + 1;
}

// ---------------- tile prefix + pad tail tiles (unchanged) -------------------
__global__ void prefix_kernel(const int* __restrict__ cnt, int* __restrict__ tile,
                              int* __restrict__ toklist, int* __restrict__ sellist)
{
  __shared__ int off[NB+1];
  if (threadIdx.x == 0) {
    int a = 0;
    for (int c = 0; c < NB; c++) { off[c] = a; tile[c] = a; a += (cnt[c] + 63) >> 6; }
    off[NB] = a; tile[NB] = a;
  }
  __syncthreads();
  for (int c = 0; c < NB; c++) {
    const int s = cnt[c], e = (off[c+1] - off[c]) << 6;
    for (int i = s + threadIdx.x; i < e; i += 256) {
      toklist[c*TOK + i] = 0;
      sellist[c*TOK + i] = 2*TOK + c*64 + (i & 63);
    }
  }
}

// ---------------- W split-cast (unchanged) -----------------------------------
__global__ void wcast_kernel(const float* __restrict__ Wkv,
                             const float* __restrict__ Wb,
                             short* __restrict__ Whi, short* __restrict__ Wlo)
{
  const int R = blockIdx.x, c = R/192, r = R%192;
  const float* src = (r < 128) ? Wkv + ((size_t)c*128 + r)*DIM
                               : Wb  + ((size_t)c*64 + (r-128))*DIM;
  const int k = threadIdx.x*4;
  float4 f = *(const float4*)&src[k];
  float ff[4] = {f.x, f.y, f.z, f.w};
  short* dh = Whi + (size_t)R*DIM + k;
  short* dl = Wlo + (size_t)R*DIM + k;
  #pragma unroll
  for (int e = 0; e < 4; e++) {
    float rem;
    dh[e] = f2bf_hi(ff[e], rem);
    dl[e] = f2bf(rem);
  }
}

// ---------------- gather-GEMM: bf16x3 MFMA (unchanged) ----------------------
__global__ __launch_bounds__(256) void gather_gemm_kernel(
    const float* __restrict__ x,
    const short* __restrict__ Whi, const short* __restrict__ Wlo,
    const float* __restrict__ b_beta,
    const int* __restrict__ tileoff, const int* __restrict__ toklist,
    const int* __restrict__ sellist, float* __restrict__ kvsel)
{
  __shared__ short Ahi[64][40];
  __shared__ short Alo[64][40];
  __shared__ int tl[64], sl[64];
  const int tile = blockIdx.x;
  if (tile >= tileoff[NB]) return;
  int c = 0;
  while (c < NB-1 && tile >= tileoff[c+1]) c++;
  const int ti = tile - tileoff[c];
  const int tid = threadIdx.x;
  if (tid < 64) {
    tl[tid] = toklist[c*TOK + (ti<<6) + tid];
    sl[tid] = sellist[c*TOK + (ti<<6) + tid];
  }
  __syncthreads();

  const int wv = tid >> 6, l = tid & 63;
  const int arow = tid >> 2, akseg = (tid & 3) << 3;
  const float* aptr = x + (size_t)tl[arow]*DIM + akseg;
  const short* bh_p = Whi + ((size_t)c*192 + wv*48 + (l & 15))*DIM + ((l >> 4) << 3);
  const short* bl_p = Wlo + ((size_t)c*192 + wv*48 + (l & 15))*DIM + ((l >> 4) << 3);

  f32x4 acc[4][3];
  #pragma unroll
  for (int mt = 0; mt < 4; mt++)
    #pragma unroll
    for (int nt = 0; nt < 3; nt++) acc[mt][nt] = (f32x4){0.f,0.f,0.f,0.f};

  float4 af[2][2];
  short8x bh[2][3], bl[2][3];
  af[0][0] = *(const float4*)&aptr[0];
  af[0][1] = *(const float4*)&aptr[4];
  #pragma unroll
  for (int nt = 0; nt < 3; nt++) {
    bh[0][nt] = *(const short8x*)&bh_p[nt*16*DIM];
    bl[0][nt] = *(const short8x*)&bl_p[nt*16*DIM];
  }

  #pragma unroll 2
  for (int ch = 0; ch < 32; ch++) {
    const int p = ch & 1, pn = p ^ 1;
    {
      float f8[8] = {af[p][0].x, af[p][0].y, af[p][0].z, af[p][0].w,
                     af[p][1].x, af[p][1].y, af[p][1].z, af[p][1].w};
      short h8[8], l8[8];
      #pragma unroll
      for (int e = 0; e < 8; e++) {
        float rem;
        h8[e] = f2bf_hi(f8[e], rem);
        l8[e] = f2bf(rem);
      }
      *(short8x*)&Ahi[arow][akseg] = *(short8x*)h8;
      *(short8x*)&Alo[arow][akseg] = *(short8x*)l8;
    }
    if (ch < 31) {
      af[pn][0] = *(const float4*)&aptr[(ch+1)*32];
      af[pn][1] = *(const float4*)&aptr[(ch+1)*32 + 4];
    }
    __syncthreads();
    if (ch < 31) {
      #pragma unroll
      for (int nt = 0; nt < 3; nt++) {
        bh[pn][nt] = *(const short8x*)&bh_p[nt*16*DIM + (ch+1)*32];
        bl[pn][nt] = *(const short8x*)&bl_p[nt*16*DIM + (ch+1)*32];
      }
    }
    short8x ah[4], al[4];
    #pragma unroll
    for (int mt = 0; mt < 4; mt++) {
      ah[mt] = *(const short8x*)&Ahi[mt*16 + (l & 15)][(l >> 4) << 3];
      al[mt] = *(const short8x*)&Alo[mt*16 + (l & 15)][(l >> 4) << 3];
    }
    #pragma unroll
    for (int mt = 0; mt < 4; mt++)
      #pragma unroll
      for (int nt = 0; nt < 3; nt++) {
        acc[mt][nt] = __builtin_amdgcn_mfma_f32_16x16x32_bf16(ah[mt], bh[p][nt], acc[mt][nt], 0, 0, 0);
        acc[mt][nt] = __builtin_amdgcn_mfma_f32_16x16x32_bf16(ah[mt], bl[p][nt], acc[mt][nt], 0, 0, 0);
        acc[mt][nt] = __builtin_amdgcn_mfma_f32_16x16x32_bf16(al[mt], bh[p][nt], acc[mt][nt], 0, 0, 0);
      }
    __syncthreads();
  }

  #pragma unroll
  for (int mt = 0; mt < 4; mt++) {
    #pragma unroll
    for (int reg = 0; reg < 4; reg++) {
      const int row = mt*16 + (l >> 4)*4 + reg;
      const int srow = sl[row];
      #pragma unroll
      for (int nt = 0; nt < 3; nt++) {
        const int col = wv*48 + nt*16 + (l & 15);
        float vvv = acc[mt][nt][reg];
        if (col >= 128) vvv += b_beta[c*64 + (col - 128)];
        kvsel[(size_t)srow*192 + col] = vvv;
      }
    }
  }
}

// ---------------- dense fp32 SGEMM for q (unchanged) -------------------------
__global__ __launch_bounds__(256) void sgemm_kernel(
    const float* __restrict__ A, const float* __restrict__ B,
    float* __restrict__ C, int N, int K)
{
  __shared__ __align__(16) float As[16][68];
  __shared__ __align__(16) float Bs[16][68];
  const int tid = threadIdx.x;
  const int tx = tid & 15, ty = tid >> 4;
  const int m0 = blockIdx.x << 6, n0 = blockIdx.y << 6;
  const int lr = tid >> 2, lk = (tid & 3) << 2;
  float acc[4][4] = {{0.f,0.f,0.f,0.f},{0.f,0.f,0.f,0.f},
                     {0.f,0.f,0.f,0.f},{0.f,0.f,0.f,0.f}};
  for (int k0 = 0; k0 < K; k0 += 16) {
    float4 a = *(const float4*)&A[(size_t)(m0+lr)*K + k0 + lk];
    float4 b = *(const float4*)&B[(size_t)(n0+lr)*K + k0 + lk];
    As[lk+0][lr]=a.x; As[lk+1][lr]=a.y; As[lk+2][lr]=a.z; As[lk+3][lr]=a.w;
    Bs[lk+0][lr]=b.x; Bs[lk+1][lr]=b.y; Bs[lk+2][lr]=b.z; Bs[lk+3][lr]=b.w;
    __syncthreads();
    #pragma unroll
    for (int kk = 0; kk < 16; kk++) {
      float4 av = *(const float4*)&As[kk][ty<<2];
      float4 bv = *(const float4*)&Bs[kk][tx<<2];
      acc[0][0] += av.x*bv.x; acc[0][1] += av.x*bv.y; acc[0][2] += av.x*bv.z; acc[0][3] += av.x*bv.w;
      acc[1][0] += av.y*bv.x; acc[1][1] += av.y*bv.y; acc[1][2] += av.y*bv.z; acc[1][3] += av.y*bv.w;
      acc[2][0] += av.z*bv.x; acc[2][1] += av.z*bv.y; acc[2][2] += av.z*bv.z; acc[2][3] += av.z*bv.w;
      acc[3][0] += av.w*bv.x; acc[3][1] += av.w*bv.y; acc[3][2] += av.w*bv.z; acc[3][3] += av.w*bv.w;
    }
    __syncthreads();
  }
  #pragma unroll
  for (int u = 0; u < 4; u++)
    *(float4*)&C[(size_t)(m0 + (ty<<2) + u)*N + n0 + (tx<<2)] =
        make_float4(acc[u][0], acc[u][1], acc[u][2], acc[u][3]);
}

// ---------------- recurrence v8: v7 diet + 4 waves/SIMD ----------------------
// Block = 1024 thr = 16 waves = 4 tasks (same b, shared ldsO -> flush volume
// unchanged vs v7). Each task split over 4 waves: wave h owns S-rows
// h*16..h*16+15; lane (jq=l>>4, rl=l&15) owns 16 S elems; dots = 16 FMA +
// shfl_xor(16)+(32). Grid 256 -> 1 block/CU -> 16 waves/CU = 4/SIMD (v7: 2).
// Diet kept: ballot sel-masks, w-chunk shfl broadcast, q pointer-bump.
__global__ __launch_bounds__(1024, 1) void recur_kernel(
    const int* __restrict__ selp,     // [TOK] m1|m2<<8
    const float* __restrict__ w,      // [TOK][16]
    const float* __restrict__ kvsel,  // [SELROWS][192]
    const float* __restrict__ qb,     // [TOK][64]
    float* __restrict__ out,          // [TOK][64] accum (pre-zeroed)
    float* __restrict__ Sfin)         // [B][16][64][64]
{
  const int wv = threadIdx.x >> 6, lane = threadIdx.x & 63;
  const int tt = wv >> 2, h = wv & 3;            // task-in-block, row-quarter
  const int task = blockIdx.x*4 + tt, b = task >> 4, c = task & 15;
  const int rl = lane & 15, jq = lane >> 4;      // row-in-wave, j-quarter
  const int row = h*16 + rl;                     // S row this lane owns
  __shared__ __align__(16) float ldsQ[16][2][64];
  __shared__ __align__(16) float ldsK[16][2][64];
  __shared__ __align__(16) float ldsO[64][64];   // 16 KB window, 4 tasks (same b)

  float S[16];                                   // S[row][jq*16 + 0..15]
  #pragma unroll
  for (int j = 0; j < 16; j++) S[j] = 0.f;

  const int*   sp = selp + b;                    // stride 64 per t
  const float* wp = w  + (size_t)b*NB + c;       // stride 1024 per t
  const float* qp = qb + (size_t)b*NS + lane;    // staging (lane = j)
  float*       op = out + (size_t)b*NS + lane;   // flush (lane = outdim)

  // zero output window: 4 rows per wave
  #pragma unroll
  for (int r = 0; r < 4; r++) ldsO[(wv<<2) + r][lane] = 0.f;

  // ---- per-chunk ballot masks: bit L of chunk = step ch*64+L ---------------
  unsigned long long selA, selB, slotA, slotB;
  {
    int nv0 = sp[(size_t)lane*64];
    int nv1 = sp[(size_t)(64 + lane)*64];
    bool p2a = (c == (nv0 >> 8)), pa = (c == (nv0 & 255)) || p2a;
    bool p2b = (c == (nv1 >> 8)), pb = (c == (nv1 & 255)) || p2b;
    selA = __ballot(pa);  slotA = __ballot(p2a);
    selB = __ballot(pb);  slotB = __ballot(p2b);
  }
  auto SEL = [&](int tti) -> bool {
    const unsigned long long m = ((tti >> 6) & 1) ? selB : selA;
    return (m >> (tti & 63)) & 1ull;
  };
  auto SLOT = [&](int tti) -> int {
    const unsigned long long m = ((tti >> 6) & 1) ? slotB : slotA;
    return (int)((m >> (tti & 63)) & 1ull);
  };

  // ---- w chunks (lane L of chunk ch holds w[(ch*64+L), c]) -----------------
  float wA = wp[(size_t)lane*1024];
  float wB = wp[(size_t)(64 + lane)*1024];

  float kk[4], vf[4], bf_[4], qq[4], bet[2];

  #pragma unroll
  for (int i = 0; i < 3; i++) {
    qq[i] = qp[(size_t)i*4096];
    if (SEL(i)) {
      const float* r = kvsel + ((size_t)2*(i*BATCH + b) + SLOT(i))*192;
      kk[i]  = r[lane];        // j-indexed (for norm + stage)
      vf[i]  = r[64 + row];    // row-indexed
      bf_[i] = r[128 + row];   // row-indexed
    }
  }
  bet[0] = bet[1] = 0.f;
  ldsQ[wv][0][lane] = qq[0];
  if (selA & 1ull) {
    float s2 = kk[0]*kk[0];
    #pragma unroll
    for (int o = 32; o; o >>= 1) s2 += __shfl_xor(s2, o);
    ldsK[wv][0][lane] = kk[0]*__builtin_amdgcn_rcpf(sqrtf(s2) + 1e-6f);
    bet[0] = sigm(bf_[0]);
  }
  const float* qpp = qp + (size_t)3*4096;
  __syncthreads();   // ldsO zeroed before any ds_add

  #pragma unroll 2
  for (int t = 0; t < T_STEPS; t++) {
    const int i0 = t & 3, i1 = (t+1) & 3, i3 = (t+3) & 3;
    // ---- chunk refill: sel/slot masks + w, 61+ steps before first use ------
    if ((t & 63) == 0 && t) {
      const int nc = (t >> 6) + 1;
      int nv = sp[(size_t)(nc*64 + lane)*64];
      float nw = wp[(size_t)(nc*64 + lane)*1024];
      bool p2 = (c == (nv >> 8)), pr = (c == (nv & 255)) || p2;
      unsigned long long ms = __ballot(pr), m2 = __ballot(p2);
      if (nc & 1) { selB = ms; slotB = m2; wB = nw; }
      else        { selA = ms; slotA = m2; wA = nw; }
    }
    // ---- prefetch data t+3 -------------------------------------------------
    qq[i3] = *qpp; qpp += 4096;
    if (SEL(t+3)) {
      const float* r = kvsel + ((size_t)2*((t+3)*BATCH + b) + SLOT(t+3))*192;
      kk[i3]  = r[lane];
      vf[i3]  = r[64 + row];
      bf_[i3] = r[128 + row];
    }
    // ---- stage t+1 (k loaded 2 iters ago: norm off critical path) ----------
    ldsQ[wv][(t+1) & 1][lane] = qq[i1];
    if (SEL(t+1)) {
      float s2 = kk[i1]*kk[i1];
      #pragma unroll
      for (int o = 32; o; o >>= 1) s2 += __shfl_xor(s2, o);
      ldsK[wv][(t+1) & 1][lane] = kk[i1]*__builtin_amdgcn_rcpf(sqrtf(s2) + 1e-6f);
      bet[(t+1) & 1] = sigm(bf_[i1]);
    }
    // ---- compute step t (16 elems/lane + 2 shfl) ---------------------------
    if (SEL(t)) {
      const float* kr = &ldsK[wv][t & 1][jq << 4];
      float aa[4] = {0.f, 0.f, 0.f, 0.f};
      #pragma unroll
      for (int j = 0; j < 16; j += 4) {
        float4 k4 = *(const float4*)&kr[j];
        aa[j>>2] = fmaf(S[j+3], k4.w, fmaf(S[j+2], k4.z,
                   fmaf(S[j+1], k4.y, fmaf(S[j+0], k4.x, aa[j>>2]))));
      }
      float r = (aa[0] + aa[1]) + (aa[2] + aa[3]);
      r += __shfl_xor(r, 16);                     // combine j-quarters
      r += __shfl_xor(r, 32);
      const float g = vf[i0] - r;
      const float be = bet[t & 1];
      #pragma unroll
      for (int j = 0; j < 16; j += 4) {
        float4 k4 = *(const float4*)&kr[j];
        S[j+0] = fast_tanh(fmaf(be, S[j+0], g*k4.x));
        S[j+1] = fast_tanh(fmaf(be, S[j+1], g*k4.y));
        S[j+2] = fast_tanh(fmaf(be, S[j+2], g*k4.z));
        S[j+3] = fast_tanh(fmaf(be, S[j+3], g*k4.w));
      }
    }
    // ---- output: Sq, silu-gate, LDS-window accumulate ----------------------
    {
      const float* qr = &ldsQ[wv][t & 1][jq << 4];
      float aa[4] = {0.f, 0.f, 0.f, 0.f};
      #pragma unroll
      for (int j = 0; j < 16; j += 4) {
        float4 q4 = *(const float4*)&qr[j];
        aa[j>>2] = fmaf(S[j+3], q4.w, fmaf(S[j+2], q4.z,
                   fmaf(S[j+1], q4.y, fmaf(S[j+0], q4.x, aa[j>>2]))));
      }
      float sq = (aa[0] + aa[1]) + (aa[2] + aa[3]);
      sq += __shfl_xor(sq, 16);                   // combine j-quarters
      sq += __shfl_xor(sq, 32);
      const float bo = sq*sq*sigm(sq);
      const float wcur = __shfl(((t >> 6) & 1) ? wB : wA, t & 63);
      if (jq == 0)
        unsafeAtomicAdd(&ldsO[t & 63][row], wcur*bo);
    }
    // ---- window flush every 64 steps ---------------------------------------
    if ((t & 63) == 63) {
      __syncthreads();
      const int t0 = t & ~63;
      #pragma unroll
      for (int r = 0; r < 4; r++) {
        const int wrow = (wv<<2) + r;
        unsafeAtomicAdd(&op[(size_t)(t0 + wrow)*4096], ldsO[wrow][lane]);
        ldsO[wrow][lane] = 0.f;
      }
      __syncthreads();
    }
  }

  // Sfin: lane writes its 16 j's of its row
  float* dst = Sfin + (((size_t)b*NB + c)*NS + row)*NS + (jq << 4);
  #pragma unroll
  for (int j = 0; j < 16; j += 4)
    *(float4*)&dst[j] = make_float4(S[j], S[j+1], S[j+2], S[j+3]);
}

extern "C" void kernel_launch(void* const* d_in, const int* in_sizes, int n_in,
                              void* d_out, int out_size, void* d_ws, size_t ws_size,
                              hipStream_t stream) {
  const float* x        = (const float*)d_in[0];
  const float* W_router = (const float*)d_in[1];
  const float* W_kv     = (const float*)d_in[2];
  const float* W_beta   = (const float*)d_in[3];
  const float* b_beta   = (const float*)d_in[4];
  const float* W_q      = (const float*)d_in[5];

  float* out  = (float*)d_out;
  float* Sfin = out + (size_t)TOK*NS;
  float* ws     = (float*)d_ws;
  float* logits = ws + WS_LOGITS;
  float* wsm    = ws + WS_W;
  float* qb     = ws + WS_Q;
  int*   selp   = (int*)(ws + WS_SEL);
  int*   toklist= (int*)(ws + WS_TOKL);
  int*   sellist= (int*)(ws + WS_SELL);
  int*   cnt    = (int*)(ws + WS_CNT);
  int*   tile   = (int*)(ws + WS_TILE);
  float* kvsel  = ws + WS_KVSEL;
  short* Whi    = (short*)(ws + WS_WHI);
  short* Wlo    = (short*)(ws + WS_WLO);

  hipMemsetAsync(out, 0, (size_t)TOK*NS*sizeof(float), stream);
  hipMemsetAsync(cnt, 0, 16*sizeof(int), stream);

  logits_kernel<<<TOK/64, 256, 0, stream>>>(x, W_router, logits);
  sgemm_kernel<<<dim3(TOK/64, 1), 256, 0, stream>>>(x, W_q, qb, NS, DIM);
  wcast_kernel<<<NB*192, 256, 0, stream>>>(W_kv, W_beta, Whi, Wlo);
  route_kernel<<<TOK/256, 256, 0, stream>>>(logits, wsm, selp, toklist, sellist, cnt);
  prefix_kernel<<<1, 256, 0, stream>>>(cnt, tile, toklist, sellist);
  gather_gemm_kernel<<<MAXTILES, 256, 0, stream>>>(
      x, Whi, Wlo, b_beta, tile, toklist, sellist, kvsel);
  recur_kernel<<<(BATCH*NB)/4, 1024, 0, stream>>>(selp, wsm, kvsel, qb, out, Sfin);
}

// Round 10
// 881.318 us; speedup vs baseline: 1.4098x; 1.2800x over previous
//
#include <hip/hip_runtime.h>
#include <hip/hip_bf16.h>
#include <math.h>

#define T_STEPS 512
#define BATCH   64
#define DIM     1024
#define NB      16
#define NS      64
#define TOK     (T_STEPS*BATCH)        // 32768
#define SELROWS (2*TOK + NB*64)        // 66560 (spare rows for tile padding)
#define MAXTILES ((2*TOK)/64 + NB)     // 1040

// ---- workspace layout (float offsets) ----
#define WS_LOGITS 0                        // TOK*16
#define WS_W      (WS_LOGITS + TOK*NB)     // TOK*16 softmax weights
#define WS_Q      (WS_W + TOK*NB)          // TOK*64
#define WS_SEL    (WS_Q + TOK*NS)          // TOK ints (m1|m2<<8)
#define WS_TOKL   (WS_SEL + TOK)           // NB*TOK ints
#define WS_SELL   (WS_TOKL + NB*TOK)       // NB*TOK ints
#define WS_CNT    (WS_SELL + NB*TOK)       // 16 ints
#define WS_TILE   (WS_CNT + 16)            // 32 ints
#define WS_KVSEL  (WS_TILE + 32)           // SELROWS*192 floats
#define WS_WHI    (WS_KVSEL + SELROWS*192) // bf16 weights
#define WS_WLO    (WS_WHI + (NB*192*DIM)/2)

typedef __attribute__((ext_vector_type(8))) short short8x;
typedef __attribute__((ext_vector_type(4))) float f32x4;

__device__ __forceinline__ short f2bf_hi(float f, float& rem) {
  __hip_bfloat16 h = __float2bfloat16(f);
  rem = f - __bfloat162float(h);
  return *(short*)&h;
}
__device__ __forceinline__ short f2bf(float f) {
  __hip_bfloat16 h = __float2bfloat16(f);
  return *(short*)&h;
}
__device__ __forceinline__ float sigm(float x) {
  return __builtin_amdgcn_rcpf(1.f + __builtin_amdgcn_exp2f(-1.4426950408889634f*x));
}
__device__ __forceinline__ float fast_tanh(float v) {
  v = fminf(10.f, fmaxf(-10.f, v));
  float e = __builtin_amdgcn_exp2f(2.8853900817779268f*v);
  return 1.f - 2.f*__builtin_amdgcn_rcpf(e + 1.f);
}

// ---------------- fused front: logits (512) + q-sgemm (512) + wcast (3072) --
// All three read only kernel inputs and write disjoint outputs -> fusable.
__global__ __launch_bounds__(256) void front_kernel(
    const float* __restrict__ x,  const float* __restrict__ Wr,
    const float* __restrict__ Wq, const float* __restrict__ Wkv,
    const float* __restrict__ Wb,
    float* __restrict__ logits, float* __restrict__ qb,
    short* __restrict__ Whi, short* __restrict__ Wlo)
{
  __shared__ __align__(16) float As[16][68];
  __shared__ __align__(16) float Bs[16][68];
  const int blk = blockIdx.x;
  const int tid = threadIdx.x;

  if (blk < 512) {
    // ---- router logits: fp64 acc, W broadcast ----
    const int wv   = __builtin_amdgcn_readfirstlane(tid >> 6);
    const int lane = tid & 63;
    const int tok  = blk*64 + lane;
    const float* xr = x + (size_t)tok*DIM;
    const float* w0 = Wr + (size_t)(4*wv)*DIM;
    double acc[4] = {0.0, 0.0, 0.0, 0.0};
    for (int k0 = 0; k0 < DIM; k0 += 32) {
      float4 xv[8];
      #pragma unroll
      for (int i = 0; i < 8; i++) xv[i] = *(const float4*)&xr[k0 + 4*i];
      #pragma unroll
      for (int cc = 0; cc < 4; cc++) {
        const float* wr = w0 + (size_t)cc*DIM + k0;
        double s = 0.0;
        #pragma unroll
        for (int i = 0; i < 8; i++) {
          float4 w4 = *(const float4*)&wr[4*i];
          s += ((double)xv[i].x*(double)w4.x + (double)xv[i].y*(double)w4.y)
             + ((double)xv[i].z*(double)w4.z + (double)xv[i].w*(double)w4.w);
        }
        acc[cc] += s;
      }
    }
    #pragma unroll
    for (int cc = 0; cc < 4; cc++)
      logits[(size_t)tok*NB + 4*wv + cc] = (float)acc[cc];
  } else if (blk < 1024) {
    // ---- dense fp32 SGEMM: qb = x . Wq^T (64 cols, K=1024) ----
    const int bx = blk - 512;
    const int tx = tid & 15, ty = tid >> 4;
    const int m0 = bx << 6, n0 = 0;
    const int lr = tid >> 2, lk = (tid & 3) << 2;
    float acc[4][4] = {{0.f,0.f,0.f,0.f},{0.f,0.f,0.f,0.f},
                       {0.f,0.f,0.f,0.f},{0.f,0.f,0.f,0.f}};
    for (int k0 = 0; k0 < DIM; k0 += 16) {
      float4 a = *(const float4*)&x [(size_t)(m0+lr)*DIM + k0 + lk];
      float4 b = *(const float4*)&Wq[(size_t)(n0+lr)*DIM + k0 + lk];
      As[lk+0][lr]=a.x; As[lk+1][lr]=a.y; As[lk+2][lr]=a.z; As[lk+3][lr]=a.w;
      Bs[lk+0][lr]=b.x; Bs[lk+1][lr]=b.y; Bs[lk+2][lr]=b.z; Bs[lk+3][lr]=b.w;
      __syncthreads();
      #pragma unroll
      for (int kk = 0; kk < 16; kk++) {
        float4 av = *(const float4*)&As[kk][ty<<2];
        float4 bv = *(const float4*)&Bs[kk][tx<<2];
        acc[0][0] += av.x*bv.x; acc[0][1] += av.x*bv.y; acc[0][2] += av.x*bv.z; acc[0][3] += av.x*bv.w;
        acc[1][0] += av.y*bv.x; acc[1][1] += av.y*bv.y; acc[1][2] += av.y*bv.z; acc[1][3] += av.y*bv.w;
        acc[2][0] += av.z*bv.x; acc[2][1] += av.z*bv.y; acc[2][2] += av.z*bv.z; acc[2][3] += av.z*bv.w;
        acc[3][0] += av.w*bv.x; acc[3][1] += av.w*bv.y; acc[3][2] += av.w*bv.z; acc[3][3] += av.w*bv.w;
      }
      __syncthreads();
    }
    #pragma unroll
    for (int u = 0; u < 4; u++)
      *(float4*)&qb[(size_t)(m0 + (ty<<2) + u)*NS + n0 + (tx<<2)] =
          make_float4(acc[u][0], acc[u][1], acc[u][2], acc[u][3]);
  } else {
    // ---- W split-cast: fp32 -> bf16 hi/lo ----
    const int R = blk - 1024, c = R/192, r = R%192;
    const float* src = (r < 128) ? Wkv + ((size_t)c*128 + r)*DIM
                                 : Wb  + ((size_t)c*64 + (r-128))*DIM;
    const int k = tid*4;
    float4 f = *(const float4*)&src[k];
    float ff[4] = {f.x, f.y, f.z, f.w};
    short* dh = Whi + (size_t)R*DIM + k;
    short* dl = Wlo + (size_t)R*DIM + k;
    #pragma unroll
    for (int e = 0; e < 4; e++) {
      float rem;
      dh[e] = f2bf_hi(ff[e], rem);
      dl[e] = f2bf(rem);
    }
  }
}

// ---------------- routing v2: LDS-aggregated counters ------------------------
// 65536 same-address global atomics -> 2048 (one per block per c). toklist
// ordering changes (block-local) which is semantically irrelevant.
__global__ __launch_bounds__(256) void route_kernel(
    const float* __restrict__ logits, float* __restrict__ w,
    int* __restrict__ selp, int* __restrict__ toklist,
    int* __restrict__ sellist, int* __restrict__ cnt)
{
  __shared__ int lcnt[NB], lbase[NB];
  const int tid = threadIdx.x;
  const int tok = blockIdx.x*256 + tid;
  const float* lg = logits + (size_t)tok*NB;
  float lv[NB];
  #pragma unroll
  for (int l = 0; l < NB; l++) lv[l] = lg[l];
  float v1 = lv[0]; int m1 = 0;
  #pragma unroll
  for (int l = 1; l < NB; l++) if (lv[l] > v1) { v1 = lv[l]; m1 = l; }
  float v2 = -3.4e38f; int m2 = 0;
  #pragma unroll
  for (int l = 0; l < NB; l++) if (l != m1 && lv[l] > v2) { v2 = lv[l]; m2 = l; }
  float ev[NB], sum = 0.f;
  #pragma unroll
  for (int l = 0; l < NB; l++) { ev[l] = __expf(lv[l] - v1); sum += ev[l]; }
  const float rs = __builtin_amdgcn_rcpf(sum);
  #pragma unroll
  for (int l = 0; l < NB; l++) w[(size_t)tok*NB + l] = ev[l] * rs;
  selp[tok] = m1 | (m2 << 8);

  if (tid < NB) lcnt[tid] = 0;
  __syncthreads();
  int p1 = atomicAdd(&lcnt[m1], 1);
  int p2 = atomicAdd(&lcnt[m2], 1);
  __syncthreads();
  if (tid < NB) lbase[tid] = atomicAdd(&cnt[tid], lcnt[tid]);
  __syncthreads();
  int o1 = lbase[m1] + p1, o2 = lbase[m2] + p2;
  toklist[m1*TOK + o1] = tok;  sellist[m1*TOK + o1] = 2*tok;
  toklist[m2*TOK + o2] = tok;  sellist[m2*TOK + o2] = 2*tok + 1;
}

// ---------------- tile prefix + pad tail tiles (unchanged) -------------------
__global__ void prefix_kernel(const int* __restrict__ cnt, int* __restrict__ tile,
                              int* __restrict__ toklist, int* __restrict__ sellist)
{
  __shared__ int off[NB+1];
  if (threadIdx.x == 0) {
    int a = 0;
    for (int c = 0; c < NB; c++) { off[c] = a; tile[c] = a; a += (cnt[c] + 63) >> 6; }
    off[NB] = a; tile[NB] = a;
  }
  __syncthreads();
  for (int c = 0; c < NB; c++) {
    const int s = cnt[c], e = (off[c+1] - off[c]) << 6;
    for (int i = s + threadIdx.x; i < e; i += 256) {
      toklist[c*TOK + i] = 0;
      sellist[c*TOK + i] = 2*TOK + c*64 + (i & 63);
    }
  }
}

// ---------------- gather-GEMM: bf16x3 MFMA (unchanged) ----------------------
__global__ __launch_bounds__(256) void gather_gemm_kernel(
    const float* __restrict__ x,
    const short* __restrict__ Whi, const short* __restrict__ Wlo,
    const float* __restrict__ b_beta,
    const int* __restrict__ tileoff, const int* __restrict__ toklist,
    const int* __restrict__ sellist, float* __restrict__ kvsel)
{
  __shared__ short Ahi[64][40];
  __shared__ short Alo[64][40];
  __shared__ int tl[64], sl[64];
  const int tile = blockIdx.x;
  if (tile >= tileoff[NB]) return;
  int c = 0;
  while (c < NB-1 && tile >= tileoff[c+1]) c++;
  const int ti = tile - tileoff[c];
  const int tid = threadIdx.x;
  if (tid < 64) {
    tl[tid] = toklist[c*TOK + (ti<<6) + tid];
    sl[tid] = sellist[c*TOK + (ti<<6) + tid];
  }
  __syncthreads();

  const int wv = tid >> 6, l = tid & 63;
  const int arow = tid >> 2, akseg = (tid & 3) << 3;
  const float* aptr = x + (size_t)tl[arow]*DIM + akseg;
  const short* bh_p = Whi + ((size_t)c*192 + wv*48 + (l & 15))*DIM + ((l >> 4) << 3);
  const short* bl_p = Wlo + ((size_t)c*192 + wv*48 + (l & 15))*DIM + ((l >> 4) << 3);

  f32x4 acc[4][3];
  #pragma unroll
  for (int mt = 0; mt < 4; mt++)
    #pragma unroll
    for (int nt = 0; nt < 3; nt++) acc[mt][nt] = (f32x4){0.f,0.f,0.f,0.f};

  float4 af[2][2];
  short8x bh[2][3], bl[2][3];
  af[0][0] = *(const float4*)&aptr[0];
  af[0][1] = *(const float4*)&aptr[4];
  #pragma unroll
  for (int nt = 0; nt < 3; nt++) {
    bh[0][nt] = *(const short8x*)&bh_p[nt*16*DIM];
    bl[0][nt] = *(const short8x*)&bl_p[nt*16*DIM];
  }

  #pragma unroll 2
  for (int ch = 0; ch < 32; ch++) {
    const int p = ch & 1, pn = p ^ 1;
    {
      float f8[8] = {af[p][0].x, af[p][0].y, af[p][0].z, af[p][0].w,
                     af[p][1].x, af[p][1].y, af[p][1].z, af[p][1].w};
      short h8[8], l8[8];
      #pragma unroll
      for (int e = 0; e < 8; e++) {
        float rem;
        h8[e] = f2bf_hi(f8[e], rem);
        l8[e] = f2bf(rem);
      }
      *(short8x*)&Ahi[arow][akseg] = *(short8x*)h8;
      *(short8x*)&Alo[arow][akseg] = *(short8x*)l8;
    }
    if (ch < 31) {
      af[pn][0] = *(const float4*)&aptr[(ch+1)*32];
      af[pn][1] = *(const float4*)&aptr[(ch+1)*32 + 4];
    }
    __syncthreads();
    if (ch < 31) {
      #pragma unroll
      for (int nt = 0; nt < 3; nt++) {
        bh[pn][nt] = *(const short8x*)&bh_p[nt*16*DIM + (ch+1)*32];
        bl[pn][nt] = *(const short8x*)&bl_p[nt*16*DIM + (ch+1)*32];
      }
    }
    short8x ah[4], al[4];
    #pragma unroll
    for (int mt = 0; mt < 4; mt++) {
      ah[mt] = *(const short8x*)&Ahi[mt*16 + (l & 15)][(l >> 4) << 3];
      al[mt] = *(const short8x*)&Alo[mt*16 + (l & 15)][(l >> 4) << 3];
    }
    #pragma unroll
    for (int mt = 0; mt < 4; mt++)
      #pragma unroll
      for (int nt = 0; nt < 3; nt++) {
        acc[mt][nt] = __builtin_amdgcn_mfma_f32_16x16x32_bf16(ah[mt], bh[p][nt], acc[mt][nt], 0, 0, 0);
        acc[mt][nt] = __builtin_amdgcn_mfma_f32_16x16x32_bf16(ah[mt], bl[p][nt], acc[mt][nt], 0, 0, 0);
        acc[mt][nt] = __builtin_amdgcn_mfma_f32_16x16x32_bf16(al[mt], bh[p][nt], acc[mt][nt], 0, 0, 0);
      }
    __syncthreads();
  }

  #pragma unroll
  for (int mt = 0; mt < 4; mt++) {
    #pragma unroll
    for (int reg = 0; reg < 4; reg++) {
      const int row = mt*16 + (l >> 4)*4 + reg;
      const int srow = sl[row];
      #pragma unroll
      for (int nt = 0; nt < 3; nt++) {
        const int col = wv*48 + nt*16 + (l & 15);
        float vvv = acc[mt][nt][reg];
        if (col >= 128) vvv += b_beta[c*64 + (col - 128)];
        kvsel[(size_t)srow*192 + col] = vvv;
      }
    }
  }
}

// ---------------- recurrence v9: v8 + shared qwin + kvsel ptr-bump -----------
// Geometry = v8 (16 waves/block, 4 tasks same b, 4 waves/task). Diet:
//  (a) qwin[64][64]: block-shared q window staged cooperatively inside the
//      existing flush barriers -> kills per-wave-step q load + ldsQ write.
//  (b) kvsel pointer-bump (stride 24576 floats/step) replaces 64-bit offset
//      reconstruction each step.
__global__ __launch_bounds__(1024, 1) void recur_kernel(
    const int* __restrict__ selp,     // [TOK] m1|m2<<8
    const float* __restrict__ w,      // [TOK][16]
    const float* __restrict__ kvsel,  // [SELROWS][192]
    const float* __restrict__ qb,     // [TOK][64]
    float* __restrict__ out,          // [TOK][64] accum (pre-zeroed)
    float* __restrict__ Sfin)         // [B][16][64][64]
{
  const int wv = threadIdx.x >> 6, lane = threadIdx.x & 63;
  const int tt = wv >> 2, h = wv & 3;            // task-in-block, row-quarter
  const int task = blockIdx.x*4 + tt, b = task >> 4, c = task & 15;
  const int rl = lane & 15, jq = lane >> 4;      // row-in-wave, j-quarter
  const int row = h*16 + rl;                     // S row this lane owns
  __shared__ __align__(16) float ldsK[16][2][64];
  __shared__ __align__(16) float ldsO[64][64];   // 16 KB window, 4 tasks (same b)
  __shared__ __align__(16) float qwin[64][64];   // 16 KB q window (same b)

  float S[16];                                   // S[row][jq*16 + 0..15]
  #pragma unroll
  for (int j = 0; j < 16; j++) S[j] = 0.f;

  const int*   sp = selp + b;                    // stride 64 per t
  const float* wp = w  + (size_t)b*NB + c;       // stride 1024 per t
  const float* qrow = qb + (size_t)b*NS + lane;  // + t*4096
  float*       op = out + (size_t)b*NS + lane;   // flush (lane = outdim)

  // zero output window + stage q window 0 (4 rows per wave each)
  #pragma unroll
  for (int r = 0; r < 4; r++) {
    const int s = (wv<<2) + r;
    ldsO[s][lane] = 0.f;
    qwin[s][lane] = qrow[(size_t)s*4096];
  }

  // ---- per-chunk ballot masks: bit L of chunk = step ch*64+L ---------------
  unsigned long long selA, selB, slotA, slotB;
  {
    int nv0 = sp[(size_t)lane*64];
    int nv1 = sp[(size_t)(64 + lane)*64];
    bool p2a = (c == (nv0 >> 8)), pa = (c == (nv0 & 255)) || p2a;
    bool p2b = (c == (nv1 >> 8)), pb = (c == (nv1 & 255)) || p2b;
    selA = __ballot(pa);  slotA = __ballot(p2a);
    selB = __ballot(pb);  slotB = __ballot(p2b);
  }
  auto SEL = [&](int tti) -> bool {
    const unsigned long long m = ((tti >> 6) & 1) ? selB : selA;
    return (m >> (tti & 63)) & 1ull;
  };
  auto SLOT = [&](int tti) -> int {
    const unsigned long long m = ((tti >> 6) & 1) ? slotB : slotA;
    return (int)((m >> (tti & 63)) & 1ull);
  };

  // ---- w chunks (lane L of chunk ch holds w[(ch*64+L), c]) -----------------
  float wA = wp[(size_t)lane*1024];
  float wB = wp[(size_t)(64 + lane)*1024];

  float kk[4], vf[4], bf_[4], bet[2];

  // kvsel base for this b; per-t element stride = 2*BATCH*192 = 24576
  const float* kvp = kvsel + (size_t)b*384;
  #pragma unroll
  for (int i = 0; i < 3; i++) {
    if (SEL(i)) {
      const float* r = kvp + (size_t)i*24576 + (SLOT(i) ? 192 : 0);
      kk[i]  = r[lane];        // j-indexed (for norm + stage)
      vf[i]  = r[64 + row];    // row-indexed
      bf_[i] = r[128 + row];   // row-indexed
    }
  }
  bet[0] = bet[1] = 0.f;
  if (selA & 1ull) {
    float s2 = kk[0]*kk[0];
    #pragma unroll
    for (int o = 32; o; o >>= 1) s2 += __shfl_xor(s2, o);
    ldsK[wv][0][lane] = kk[0]*__builtin_amdgcn_rcpf(sqrtf(s2) + 1e-6f);
    bet[0] = sigm(bf_[0]);
  }
  const float* kvp3 = kvp + (size_t)3*24576;     // t+3 pointer, bumped per step
  __syncthreads();   // ldsO zeroed + qwin staged before use

  #pragma unroll 2
  for (int t = 0; t < T_STEPS; t++) {
    const int i0 = t & 3, i1 = (t+1) & 3, i3 = (t+3) & 3;
    // ---- chunk refill: sel/slot masks + w, 61+ steps before first use ------
    if ((t & 63) == 0 && t) {
      const int nc = (t >> 6) + 1;
      int nv = sp[(size_t)(nc*64 + lane)*64];
      float nw = wp[(size_t)(nc*64 + lane)*1024];
      bool p2 = (c == (nv >> 8)), pr = (c == (nv & 255)) || p2;
      unsigned long long ms = __ballot(pr), m2 = __ballot(p2);
      if (nc & 1) { selB = ms; slotB = m2; wB = nw; }
      else        { selA = ms; slotA = m2; wA = nw; }
    }
    // ---- prefetch kvsel t+3 (pointer-bumped) -------------------------------
    if (SEL(t+3)) {
      const float* r = kvp3 + (SLOT(t+3) ? 192 : 0);
      kk[i3]  = r[lane];
      vf[i3]  = r[64 + row];
      bf_[i3] = r[128 + row];
    }
    kvp3 += 24576;
    // ---- stage t+1 (k loaded 2 iters ago: norm off critical path) ----------
    if (SEL(t+1)) {
      float s2 = kk[i1]*kk[i1];
      #pragma unroll
      for (int o = 32; o; o >>= 1) s2 += __shfl_xor(s2, o);
      ldsK[wv][(t+1) & 1][lane] = kk[i1]*__builtin_amdgcn_rcpf(sqrtf(s2) + 1e-6f);
      bet[(t+1) & 1] = sigm(bf_[i1]);
    }
    // ---- compute step t (16 elems/lane + 2 shfl) ---------------------------
    if (SEL(t)) {
      const float* kr = &ldsK[wv][t & 1][jq << 4];
      float aa[4] = {0.f, 0.f, 0.f, 0.f};
      #pragma unroll
      for (int j = 0; j < 16; j += 4) {
        float4 k4 = *(const float4*)&kr[j];
        aa[j>>2] = fmaf(S[j+3], k4.w, fmaf(S[j+2], k4.z,
                   fmaf(S[j+1], k4.y, fmaf(S[j+0], k4.x, aa[j>>2]))));
      }
      float r = (aa[0] + aa[1]) + (aa[2] + aa[3]);
      r += __shfl_xor(r, 16);                     // combine j-quarters
      r += __shfl_xor(r, 32);
      const float g = vf[i0] - r;
      const float be = bet[t & 1];
      #pragma unroll
      for (int j = 0; j < 16; j += 4) {
        float4 k4 = *(const float4*)&kr[j];
        S[j+0] = fast_tanh(fmaf(be, S[j+0], g*k4.x));
        S[j+1] = fast_tanh(fmaf(be, S[j+1], g*k4.y));
        S[j+2] = fast_tanh(fmaf(be, S[j+2], g*k4.z));
        S[j+3] = fast_tanh(fmaf(be, S[j+3], g*k4.w));
      }
    }
    // ---- output: Sq from qwin, silu-gate, LDS-window accumulate ------------
    {
      const float* qr = &qwin[t & 63][jq << 4];
      float aa[4] = {0.f, 0.f, 0.f, 0.f};
      #pragma unroll
      for (int j = 0; j < 16; j += 4) {
        float4 q4 = *(const float4*)&qr[j];
        aa[j>>2] = fmaf(S[j+3], q4.w, fmaf(S[j+2], q4.z,
                   fmaf(S[j+1], q4.y, fmaf(S[j+0], q4.x, aa[j>>2]))));
      }
      float sq = (aa[0] + aa[1]) + (aa[2] + aa[3]);
      sq += __shfl_xor(sq, 16);                   // combine j-quarters
      sq += __shfl_xor(sq, 32);
      const float bo = sq*sq*sigm(sq);
      const float wcur = __shfl(((t >> 6) & 1) ? wB : wA, t & 63);
      if (jq == 0)
        unsafeAtomicAdd(&ldsO[t & 63][row], wcur*bo);
    }
    // ---- window flush + qwin restage every 64 steps ------------------------
    if ((t & 63) == 63) {
      __syncthreads();
      const int t0 = t & ~63;
      const int nwin = (t >> 6) + 1;
      #pragma unroll
      for (int r = 0; r < 4; r++) {
        const int wrow = (wv<<2) + r;
        unsafeAtomicAdd(&op[(size_t)(t0 + wrow)*4096], ldsO[wrow][lane]);
        ldsO[wrow][lane] = 0.f;
      }
      if (nwin < 8) {
        #pragma unroll
        for (int r = 0; r < 4; r++) {
          const int s = (wv<<2) + r;
          qwin[s][lane] = qrow[(size_t)(nwin*64 + s)*4096];
        }
      }
      __syncthreads();
    }
  }

  // Sfin: lane writes its 16 j's of its row
  float* dst = Sfin + (((size_t)b*NB + c)*NS + row)*NS + (jq << 4);
  #pragma unroll
  for (int j = 0; j < 16; j += 4)
    *(float4*)&dst[j] = make_float4(S[j], S[j+1], S[j+2], S[j+3]);
}

extern "C" void kernel_launch(void* const* d_in, const int* in_sizes, int n_in,
                              void* d_out, int out_size, void* d_ws, size_t ws_size,
                              hipStream_t stream) {
  const float* x        = (const float*)d_in[0];
  const float* W_router = (const float*)d_in[1];
  const float* W_kv     = (const float*)d_in[2];
  const float* W_beta   = (const float*)d_in[3];
  const float* b_beta   = (const float*)d_in[4];
  const float* W_q      = (const float*)d_in[5];

  float* out  = (float*)d_out;
  float* Sfin = out + (size_t)TOK*NS;
  float* ws     = (float*)d_ws;
  float* logits = ws + WS_LOGITS;
  float* wsm    = ws + WS_W;
  float* qb     = ws + WS_Q;
  int*   selp   = (int*)(ws + WS_SEL);
  int*   toklist= (int*)(ws + WS_TOKL);
  int*   sellist= (int*)(ws + WS_SELL);
  int*   cnt    = (int*)(ws + WS_CNT);
  int*   tile   = (int*)(ws + WS_TILE);
  float* kvsel  = ws + WS_KVSEL;
  short* Whi    = (short*)(ws + WS_WHI);
  short* Wlo    = (short*)(ws + WS_WLO);

  hipMemsetAsync(out, 0, (size_t)TOK*NS*sizeof(float), stream);
  hipMemsetAsync(cnt, 0, 16*sizeof(int), stream);

  front_kernel<<<512 + 512 + NB*192, 256, 0, stream>>>(
      x, W_router, W_q, W_kv, W_beta, logits, qb, Whi, Wlo);
  route_kernel<<<TOK/256, 256, 0, stream>>>(logits, wsm, selp, toklist, sellist, cnt);
  prefix_kernel<<<1, 256, 0, stream>>>(cnt, tile, toklist, sellist);
  gather_gemm_kernel<<<MAXTILES, 256, 0, stream>>>(
      x, Whi, Wlo, b_beta, tile, toklist, sellist, kvsel);
  recur_kernel<<<(BATCH*NB)/4, 1024, 0, stream>>>(selp, wsm, kvsel, qb, out, Sfin);
}